// Round 7
// baseline (2394.634 us; speedup 1.0000x reference)
//
#include <hip/hip_runtime.h>
#include <cmath>

#define NN 100000
#define NE 1600000
#define NG 512
#define H 200
#define D 205
#define EPSV 1e-5f
#define SCAN_B 1024
#define KP 224    // padded K extent for weight (B-side) buffers, bf16, zero-padded
#define LPX 208   // x copy pitch (fp32, 16B-multiple)

typedef __attribute__((ext_vector_type(8))) short short8v;
typedef __attribute__((ext_vector_type(4))) float f32x4;

#define MFMA16(a,b,c) __builtin_amdgcn_mfma_f32_16x16x32_bf16(a,b,c,0,0,0)

static __device__ __forceinline__ float sigm(float x){ return 1.0f/(1.0f+expf(-x)); }

// split fp32 -> bf16 hi (truncate) + bf16 lo (residual)
static __device__ __forceinline__ void split2(float x, unsigned short& h, unsigned short& l){
  unsigned xb = __float_as_uint(x);
  h = (unsigned short)(xb >> 16);
  float hf = __uint_as_float(xb & 0xffff0000u);
  l = (unsigned short)(__float_as_uint(x - hf) >> 16);
}

static __device__ __forceinline__ void splitv(float4 v0, float4 v1, short8v& hi, short8v& lo){
  float v[8] = {v0.x,v0.y,v0.z,v0.w,v1.x,v1.y,v1.z,v1.w};
  #pragma unroll
  for (int e = 0; e < 8; ++e){
    unsigned u = __float_as_uint(v[e]);
    hi[e] = (short)(u >> 16);
    float hf = __uint_as_float(u & 0xffff0000u);
    lo[e] = (short)(__float_as_uint(v[e] - hf) >> 16);
  }
}

static __device__ __forceinline__ void gload16(const void* src, void* dst){
  __builtin_amdgcn_global_load_lds(
      (const __attribute__((address_space(1))) unsigned int*)src,
      (__attribute__((address_space(3))) unsigned int*)dst, 16, 0, 0);
}

// ---------------- pad-copy x: [NN,205] fp32 -> [NN,208] fp32 ----------------
__global__ __launch_bounds__(256) void padx_k(const float* __restrict__ in, float* __restrict__ out){
  long i = (long)blockIdx.x*256 + threadIdx.x;
  if (i >= (long)NN*LPX) return;
  int r = (int)(i/LPX), c = (int)(i - (long)r*LPX);
  out[i] = (c < D) ? in[(size_t)r*D + c] : 0.f;
}

// ---------------- weight cvt: fp32 [rows,C] -> hi/lo bf16 [rows,KP], zero-padded ----------------
__global__ __launch_bounds__(256) void cvt_split(const float* __restrict__ in,
    unsigned short* __restrict__ hi, unsigned short* __restrict__ lo, int rows, int C){
  long i = (long)blockIdx.x*256 + threadIdx.x;
  long tot = (long)rows*KP;
  if (i >= tot) return;
  int r = (int)(i/KP), c = (int)(i - (long)r*KP);
  float v = (c < C) ? in[(size_t)r*C + c] : 0.f;
  unsigned short hh, ll; split2(v,hh,ll);
  hi[i] = hh; lo[i] = ll;
}

// ---------------- weight cvt + transpose: out[n][k]=in[k][n], [C,KP], zero-padded ----------------
__global__ __launch_bounds__(256) void cvt_tsplit(const float* __restrict__ in,
    unsigned short* __restrict__ hi, unsigned short* __restrict__ lo, int R, int C){
  int i = blockIdx.x*256 + threadIdx.x;
  if (i >= C*KP) return;
  int n = i/KP, k = i - n*KP;
  float v = (k < R) ? in[(size_t)k*C + n] : 0.f;
  unsigned short hh, ll; split2(v,hh,ll);
  hi[i] = hh; lo[i] = ll;
}

// ---------------- split-bf16 MFMA GEMM: C[M,N] = A(fp32) @ Bsplit^T ----------------
// XCD-grouped 1-D grid: all nj j-tiles of a row-panel run on ONE XCD at
// consecutive slots -> panel fetched from HBM once, re-reads hit that XCD's L2.
template<int EPIL>
__global__ __launch_bounds__(256) void mgemm(
    const float* __restrict__ A, int LP,
    const unsigned short* __restrict__ Bhi, const unsigned short* __restrict__ Blo,
    int M, int N, int nj, int npan,
    const float* __restrict__ bias,
    const float* __restrict__ bg, const float* __restrict__ bb,
    const float* __restrict__ bm, const float* __restrict__ bv,
    float* __restrict__ C)
{
  __shared__ __align__(16) float As[128*32];              // XOR-swizzled image
  __shared__ __align__(16) unsigned short Bs[2][4096];    // [comp][q*2048B + row*16B]
  const int bid = blockIdx.x;
  const int xcd = bid & 7, s = bid >> 3;
  const int pl = s / nj, jj = s - pl*nj;
  const int p = pl*8 + xcd;
  if (p >= npan) return;
  const int n0 = jj*128, r0 = p*128;
  const int tid = threadIdx.x, lane = tid & 63, wave = tid >> 6;
  const int wr = (wave>>1)*64, wc = (wave&1)*64;
  const int fr = lane & 15, fq = lane >> 4;
  f32x4 acc[4][4] = {};

  // hoisted staging descriptors (k0-invariant)
  int aoff[4], adst[4];
  #pragma unroll
  for (int i = 0; i < 4; ++i) {
    int pa = wave + 4*i;                 // A chunk 0..15
    int R  = pa*8 + (lane>>3);
    int csw = (lane&7) ^ (R&7);
    int rg = r0 + R; if (rg > M-1) rg = M-1;
    aoff[i] = rg*LP + csw*4;
    adst[i] = pa*1024;
  }
  int boff[2], bdst[2];
  #pragma unroll
  for (int i = 0; i < 2; ++i) {
    int c = wave + 4*i;                  // B chunk 0..7
    int rowgrp = c>>2, q = c&3;
    int R = rowgrp*64 + lane;
    int rg = n0 + R; if (rg > N-1) rg = N-1;
    boff[i] = rg*KP + q*8;
    bdst[i] = q*2048 + rowgrp*1024;
  }

  for (int k0 = 0; k0 < KP; k0 += 32) {
    #pragma unroll
    for (int i = 0; i < 4; ++i) gload16(A + aoff[i] + k0, (char*)As + adst[i]);
    #pragma unroll
    for (int i = 0; i < 2; ++i) gload16(Bhi + boff[i] + k0, (char*)Bs[0] + bdst[i]);
    #pragma unroll
    for (int i = 0; i < 2; ++i) gload16(Blo + boff[i] + k0, (char*)Bs[1] + bdst[i]);
    __syncthreads();
    short8v ah[4], al[4], bh[4], bl[4];
    #pragma unroll
    for (int t = 0; t < 4; ++t) {
      int row = wr + t*16 + fr;
      const char* base = (const char*)As + row*128;
      int s0 = (fq*32) ^ ((row&7)<<4);
      float4 v0 = *(const float4*)(base + s0);
      float4 v1 = *(const float4*)(base + (s0 ^ 16));
      splitv(v0, v1, ah[t], al[t]);
      int rowb = wc + t*16 + fr;
      bh[t] = *(const short8v*)((const char*)Bs[0] + fq*2048 + rowb*16);
      bl[t] = *(const short8v*)((const char*)Bs[1] + fq*2048 + rowb*16);
    }
    #pragma unroll
    for (int i = 0; i < 4; ++i)
      #pragma unroll
      for (int j = 0; j < 4; ++j) {
        acc[i][j] = MFMA16(ah[i], bh[j], acc[i][j]);
        acc[i][j] = MFMA16(ah[i], bl[j], acc[i][j]);
        acc[i][j] = MFMA16(al[i], bh[j], acc[i][j]);
      }
    __syncthreads();
  }

  #pragma unroll
  for (int i = 0; i < 4; ++i)
    #pragma unroll
    for (int j = 0; j < 4; ++j)
      #pragma unroll
      for (int q = 0; q < 4; ++q) {
        int row = r0 + wr + i*16 + fq*4 + q;
        int col = n0 + wc + j*16 + fr;
        if (row < M && col < N) {
          float c = acc[i][j][q];
          if (EPIL) {
            c += bias[col];
            c = (c - bm[col]) * (bg[col] * rsqrtf(bv[col] + EPSV)) + bb[col];
            c = fmaxf(c, 0.f);
          }
          C[(size_t)row*N + col] = c;
        }
      }
}

// ---------------- fused GRU: 6 gate-GEMMs (MFMA) + elementwise ----------------
// XCD-grouped grid, nj=7 j-tiles per 128-row panel on one XCD.
__global__ __launch_bounds__(256) void gru6(
    const float* __restrict__ agg, const float* __restrict__ hprev,
    const unsigned short* __restrict__ Wihh, const unsigned short* __restrict__ Wihl, // [600,KP]
    const unsigned short* __restrict__ Whhh, const unsigned short* __restrict__ Whhl,
    const float* __restrict__ bih, const float* __restrict__ bhh,
    int nj, int npan,
    float* __restrict__ hnew)
{
  __shared__ __align__(16) float Gs[128*32];
  __shared__ __align__(16) float Hs[128*32];
  __shared__ __align__(16) unsigned short Ws[2][6144];   // [comp][q*3072B + row*16B]
  const int bid = blockIdx.x;
  const int xcd = bid & 7, sl = bid >> 3;
  const int pl = sl / nj, jt = sl - pl*nj;
  const int p = pl*8 + xcd;
  if (p >= npan) return;
  const int j0 = jt*32, r0 = p*128;
  const int tid = threadIdx.x, lane = tid & 63, wave = tid >> 6;
  const int fr = lane & 15, fq = lane >> 4;
  f32x4 acc[6][2][2] = {};   // [gate][row-sub][col-sub]

  // hoisted staging descriptors
  int aoff[4], adst[4];
  #pragma unroll
  for (int i = 0; i < 4; ++i) {
    int pa = wave + 4*i;                 // chunk 0..15 (same geometry for Gs and Hs)
    int R  = pa*8 + (lane>>3);
    int csw = (lane&7) ^ (R&7);
    int rg = r0 + R; if (rg > NN-1) rg = NN-1;
    aoff[i] = rg*H + csw*4;
    adst[i] = pa*1024;
  }
  int woff[3], wdst[3];
  const unsigned short* sph[3];
  const unsigned short* spl[3];
  #pragma unroll
  for (int i = 0; i < 3; ++i) {
    int c = wave + 4*i;                  // W chunk 0..11
    int rowgrp = c>>2, q = c&3;
    int R = rowgrp*64 + lane;            // 0..191 = gate*32 + jj
    int gate = R>>5, jj = R&31;
    int g3 = (gate >= 3) ? gate-3 : gate;
    int jcol = j0 + jj; if (jcol > H-1) jcol = H-1;
    woff[i] = (g3*H + jcol)*KP + q*8;
    wdst[i] = q*3072 + rowgrp*1024;
    sph[i] = (gate < 3) ? Wihh : Whhh;
    spl[i] = (gate < 3) ? Wihl : Whhl;
  }

  for (int k0 = 0; k0 < KP; k0 += 32) {
    #pragma unroll
    for (int i = 0; i < 4; ++i) gload16(agg   + aoff[i] + k0, (char*)Gs + adst[i]);
    #pragma unroll
    for (int i = 0; i < 4; ++i) gload16(hprev + aoff[i] + k0, (char*)Hs + adst[i]);
    #pragma unroll
    for (int i = 0; i < 3; ++i) gload16(sph[i] + woff[i] + k0, (char*)Ws[0] + wdst[i]);
    #pragma unroll
    for (int i = 0; i < 3; ++i) gload16(spl[i] + woff[i] + k0, (char*)Ws[1] + wdst[i]);
    __syncthreads();
    short8v gh[2], gl[2], hh[2], hl[2];
    #pragma unroll
    for (int t = 0; t < 2; ++t) {
      int row = wave*32 + t*16 + fr;
      int s0 = (fq*32) ^ ((row&7)<<4);
      const char* gb = (const char*)Gs + row*128;
      const char* hb = (const char*)Hs + row*128;
      splitv(*(const float4*)(gb+s0), *(const float4*)(gb+(s0^16)), gh[t], gl[t]);
      splitv(*(const float4*)(hb+s0), *(const float4*)(hb+(s0^16)), hh[t], hl[t]);
    }
    #pragma unroll
    for (int g = 0; g < 6; ++g) {
      const char* w0 = (const char*)Ws[0] + fq*3072;
      const char* w1 = (const char*)Ws[1] + fq*3072;
      short8v b0h = *(const short8v*)(w0 + (g*32      + fr)*16);
      short8v b1h = *(const short8v*)(w0 + (g*32 + 16 + fr)*16);
      short8v b0l = *(const short8v*)(w1 + (g*32      + fr)*16);
      short8v b1l = *(const short8v*)(w1 + (g*32 + 16 + fr)*16);
      #pragma unroll
      for (int t = 0; t < 2; ++t) {
        short8v a_h = (g < 3) ? gh[t] : hh[t];
        short8v a_l = (g < 3) ? gl[t] : hl[t];
        acc[g][t][0] = MFMA16(a_h, b0h, acc[g][t][0]);
        acc[g][t][0] = MFMA16(a_h, b0l, acc[g][t][0]);
        acc[g][t][0] = MFMA16(a_l, b0h, acc[g][t][0]);
        acc[g][t][1] = MFMA16(a_h, b1h, acc[g][t][1]);
        acc[g][t][1] = MFMA16(a_h, b1l, acc[g][t][1]);
        acc[g][t][1] = MFMA16(a_l, b1h, acc[g][t][1]);
      }
    }
    __syncthreads();
  }

  #pragma unroll
  for (int ct = 0; ct < 2; ++ct) {
    int j = j0 + ct*16 + fr;
    if (j >= H) continue;
    float br  = bih[j]     + bhh[j];
    float bz  = bih[H+j]   + bhh[H+j];
    float bin = bih[2*H+j], bhn = bhh[2*H+j];
    #pragma unroll
    for (int t = 0; t < 2; ++t)
      #pragma unroll
      for (int q = 0; q < 4; ++q) {
        int row = r0 + wave*32 + t*16 + fq*4 + q;
        if (row >= NN) continue;
        float ir = acc[0][t][ct][q], iz = acc[1][t][ct][q], inn = acc[2][t][ct][q];
        float hr = acc[3][t][ct][q], hz = acc[4][t][ct][q], hn  = acc[5][t][ct][q];
        float r = sigm(ir + hr + br);
        float z = sigm(iz + hz + bz);
        float n = tanhf(inn + bin + r*(hn + bhn));
        size_t o = (size_t)row*H + j;
        float ho = hprev[o];
        hnew[o] = (1.f - z)*n + z*ho;
      }
  }
}

// ---------------- CSR build ----------------
__global__ __launch_bounds__(256) void hist_k(const int* __restrict__ dst, int* __restrict__ deg){
  int e = blockIdx.x*256 + threadIdx.x;
  if (e < NE) atomicAdd(&deg[dst[e]], 1);
}

__global__ __launch_bounds__(256) void scan1_k(const int* __restrict__ deg, int* __restrict__ part,
                                               int* __restrict__ bsum, int n){
  __shared__ int lds[256];
  int t = threadIdx.x;
  int base = blockIdx.x * SCAN_B + t*4;
  int v[4]; int s = 0;
  #pragma unroll
  for (int q = 0; q < 4; ++q){ int idx = base+q; v[q] = (idx < n) ? deg[idx] : 0; s += v[q]; }
  lds[t] = s;
  __syncthreads();
  for (int off = 1; off < 256; off <<= 1){
    int val = 0;
    if (t >= off) val = lds[t-off];
    __syncthreads();
    if (t >= off) lds[t] += val;
    __syncthreads();
  }
  if (t == 255) bsum[blockIdx.x] = lds[255];
  int run = (t == 0) ? 0 : lds[t-1];
  #pragma unroll
  for (int q = 0; q < 4; ++q){ int idx = base+q; if (idx < n) part[idx] = run; run += v[q]; }
}

__global__ void scan2_k(int* __restrict__ bsum, int nb){
  __shared__ int lds[128];
  int t = threadIdx.x;
  int v = (t < nb) ? bsum[t] : 0;
  lds[t] = v;
  __syncthreads();
  for (int off = 1; off < 128; off <<= 1){
    int val = 0;
    if (t >= off) val = lds[t-off];
    __syncthreads();
    if (t >= off) lds[t] += val;
    __syncthreads();
  }
  if (t < nb) bsum[t] = (t == 0) ? 0 : lds[t-1];
}

__global__ __launch_bounds__(256) void scan3_k(const int* __restrict__ part, const int* __restrict__ bsum,
                                               int* __restrict__ rowptr, int* __restrict__ cpos, int n){
  int i = blockIdx.x*256 + threadIdx.x;
  if (i < n){
    int v = part[i] + bsum[i >> 10];
    rowptr[i] = v;
    cpos[i] = v;
  }
  if (i == 0) rowptr[n] = NE;
}

__global__ __launch_bounds__(256) void fill_k(const int* __restrict__ src, const int* __restrict__ dst,
                                              int* __restrict__ cpos, int* __restrict__ elist){
  int e = blockIdx.x*256 + threadIdx.x;
  if (e < NE){
    int p = atomicAdd(&cpos[dst[e]], 1);
    elist[p] = src[e];
  }
}

// ---------------- gather (column-split pass): agg[n][j] = sum m[src][j], j in [coff, coff+128) ----
// Two sequential launches keep the read working set (<=51 MB) fully L3-resident.
__global__ __launch_bounds__(128) void gather_p(const float* __restrict__ m,
                                                const int* __restrict__ rowptr,
                                                const int* __restrict__ elist,
                                                float* __restrict__ agg, int coff){
  int n = blockIdx.x;
  int j = coff + threadIdx.x;
  if (j >= H) return;
  int beg = rowptr[n], end = rowptr[n+1];
  float acc = 0.f;
  for (int k = beg; k < end; ++k){
    int s = elist[k];
    acc += m[(size_t)s*H + j];
  }
  agg[(size_t)n*H + j] = acc;
}

// ---------------- pooling: one block per graph (batch sorted -> contiguous rows) ----
__global__ __launch_bounds__(256) void pool_g(
    const float* __restrict__ h, const int* __restrict__ batch,
    const float* __restrict__ g2, const float* __restrict__ b2,
    const float* __restrict__ m2, const float* __restrict__ v2,
    float* __restrict__ gmean, float* __restrict__ gmax)
{
  int g = blockIdx.x;
  int lo = 0, hi = NN;
  while (lo < hi){ int mid = (lo+hi)>>1; if (batch[mid] < g) lo = mid+1; else hi = mid; }
  int lo2 = lo, hi2 = NN;
  while (lo2 < hi2){ int mid = (lo2+hi2)>>1; if (batch[mid] < g+1) lo2 = mid+1; else hi2 = mid; }
  int j = threadIdx.x;
  if (j >= H) return;
  float s = g2[j] * rsqrtf(v2[j] + EPSV);
  float mm = m2[j], bb = b2[j];
  float sum = 0.f, mx = 0.f;
  for (int n = lo; n < hi2; ++n){
    float val = fmaxf((h[(size_t)n*H + j] - mm)*s + bb, 0.f);
    sum += val;
    mx = fmaxf(mx, val);
  }
  int c = hi2 - lo;
  gmean[g*H + j] = (c > 0) ? sum/(float)c : 0.f;
  gmax [g*H + j] = mx;
}

// ---------------- fc1 + bnf + relu ----------------
__global__ __launch_bounds__(256) void fc1_k(
    const float* __restrict__ gmean, const float* __restrict__ gmax,
    const float* __restrict__ W,
    const float* __restrict__ bias,
    const float* __restrict__ fg, const float* __restrict__ fb,
    const float* __restrict__ fm, const float* __restrict__ fv,
    float* __restrict__ out)
{
  int tid = blockIdx.x*256 + threadIdx.x;
  if (tid >= NG*H) return;
  int g = tid / H, j = tid - g*H;
  const float* wr = W + j*2*H;
  float acc = bias[j];
  for (int k = 0; k < H; ++k) acc += gmean[g*H + k] * wr[k];
  for (int k = 0; k < H; ++k) acc += gmax[g*H + k] * wr[H + k];
  float s = fg[j] * rsqrtf(fv[j] + EPSV);
  acc = (acc - fm[j]) * s + fb[j];
  out[tid] = fmaxf(acc, 0.f);
}

__global__ void fc2_k(const float* __restrict__ in, const float* __restrict__ W,
                      const float* __restrict__ bias, float* __restrict__ out)
{
  int tid = blockIdx.x*256 + threadIdx.x;
  if (tid >= NG*2) return;
  int g = tid >> 1, c = tid & 1;
  float acc = bias[c];
  const float* wr = W + c*H;
  const float* xr = in + g*H;
  for (int k = 0; k < H; ++k) acc += xr[k]*wr[k];
  out[tid] = acc;
}

extern "C" void kernel_launch(void* const* d_in, const int* in_sizes, int n_in,
                              void* d_out, int out_size, void* d_ws, size_t ws_size,
                              hipStream_t stream)
{
  const float* x     = (const float*)d_in[0];
  const int*   eidx  = (const int*)d_in[1];
  const int*   batch = (const int*)d_in[2];
  const float* projW = (const float*)d_in[3];
  const float* projb = (const float*)d_in[4];
  const float* bn1g  = (const float*)d_in[5];
  const float* bn1b  = (const float*)d_in[6];
  const float* bn1m  = (const float*)d_in[7];
  const float* bn1v  = (const float*)d_in[8];
  const float* bn2g  = (const float*)d_in[9];
  const float* bn2b  = (const float*)d_in[10];
  const float* bn2m  = (const float*)d_in[11];
  const float* bn2v  = (const float*)d_in[12];
  const float* bnfg  = (const float*)d_in[13];
  const float* bnfb  = (const float*)d_in[14];
  const float* bnfm  = (const float*)d_in[15];
  const float* bnfv  = (const float*)d_in[16];
  const float* ggcW  = (const float*)d_in[17];
  const float* wih   = (const float*)d_in[18];
  const float* whh   = (const float*)d_in[19];
  const float* bih   = (const float*)d_in[20];
  const float* bhh   = (const float*)d_in[21];
  const float* fc1W  = (const float*)d_in[22];
  const float* fc1b  = (const float*)d_in[23];
  const float* fc2W  = (const float*)d_in[24];
  const float* fc2b  = (const float*)d_in[25];

  char* wsp = (char*)d_ws;
  auto alloc = [&](size_t nbytes) {
    char* p = wsp;
    wsp += ((nbytes + 255) / 256) * 256;
    return (void*)p;
  };
  // three rotating fp32 node buffers (bufB oversized for the 208-pitch x copy)
  float* bufA = (float*)alloc((size_t)NN*H*4);
  float* bufB = (float*)alloc((size_t)NN*LPX*4);
  float* bufC = (float*)alloc((size_t)NN*H*4);
  // weights (bf16 split, zero-padded to KP)
  unsigned short* pBh   = (unsigned short*)alloc((size_t)H*KP*2);
  unsigned short* pBl   = (unsigned short*)alloc((size_t)H*KP*2);
  unsigned short* wihBh = (unsigned short*)alloc((size_t)3*H*KP*2);
  unsigned short* wihBl = (unsigned short*)alloc((size_t)3*H*KP*2);
  unsigned short* whhBh = (unsigned short*)alloc((size_t)3*H*KP*2);
  unsigned short* whhBl = (unsigned short*)alloc((size_t)3*H*KP*2);
  unsigned short* gBh[3]; unsigned short* gBl[3];
  for (int i = 0; i < 3; ++i) {
    gBh[i] = (unsigned short*)alloc((size_t)H*KP*2);
    gBl[i] = (unsigned short*)alloc((size_t)H*KP*2);
  }
  float* gmean = (float*)alloc((size_t)NG*H*4);
  float* gmax  = (float*)alloc((size_t)NG*H*4);
  float* fc1o  = (float*)alloc((size_t)NG*H*4);
  const int NB = (NN + SCAN_B - 1) / SCAN_B;
  int* deg    = (int*)alloc((size_t)NN*4);
  int* part   = (int*)alloc((size_t)NN*4);
  int* bsum   = (int*)alloc((size_t)NB*4);
  int* rowptr = (int*)alloc((size_t)(NN+1)*4);
  int* cpos   = (int*)alloc((size_t)NN*4);
  int* elist  = (int*)alloc((size_t)NE*4);

  const int* srcp = eidx;
  const int* dstp = eidx + NE;

  // ---- CSR build (reused all 3 steps) ----
  hipMemsetAsync(deg, 0, (size_t)NN*4, stream);
  hist_k<<<(NE + 255)/256, 256, 0, stream>>>(dstp, deg);
  scan1_k<<<NB, 256, 0, stream>>>(deg, part, bsum, NN);
  scan2_k<<<1, 128, 0, stream>>>(bsum, NB);
  scan3_k<<<(NN + 255)/256, 256, 0, stream>>>(part, bsum, rowptr, cpos, NN);
  fill_k<<<(NE + 255)/256, 256, 0, stream>>>(srcp, dstp, cpos, elist);

  // ---- weight splits (zero-padded K) ----
  cvt_split<<<(int)(((long)H*KP + 255)/256), 256, 0, stream>>>(projW, pBh, pBl, H, D);
  cvt_split<<<(int)(((long)3*H*KP + 255)/256), 256, 0, stream>>>(wih, wihBh, wihBl, 3*H, H);
  cvt_split<<<(int)(((long)3*H*KP + 255)/256), 256, 0, stream>>>(whh, whhBh, whhBl, 3*H, H);
  for (int i = 0; i < 3; ++i)
    cvt_tsplit<<<(H*KP + 255)/256, 256, 0, stream>>>(ggcW + (size_t)i*H*H, gBh[i], gBl[i], H, H);

  // ---- x -> padded pitch-208 copy in bufB ----
  padx_k<<<(int)(((long)NN*LPX + 255)/256), 256, 0, stream>>>(x, bufB);

  // XCD-grouped grids
  const int NPAN = (NN + 127)/128;            // 782
  const int PL8  = (NPAN + 7)/8;              // 98
  const int NJ_G = (H + 127)/128;             // 2 (gemm j-tiles)
  const int NJ_U = (H + 31)/32;               // 7 (gru j-tiles)
  const int GRID_G = 8 * NJ_G * PL8;          // 1568
  const int GRID_U = 8 * NJ_U * PL8;          // 5488

  // proj + bn1 + relu : bufB(x) -> bufA(h)
  mgemm<1><<<GRID_G, 256, 0, stream>>>(bufB, LPX, pBh, pBl, NN, H, NJ_G, NPAN,
                                       projb, bn1g, bn1b, bn1m, bn1v, bufA);

  float* h   = bufA;
  float* m   = bufB;
  float* agg = bufC;
  for (int i = 0; i < 3; ++i) {
    mgemm<0><<<GRID_G, 256, 0, stream>>>(h, H, gBh[i], gBl[i], NN, H, NJ_G, NPAN,
                                         nullptr, nullptr, nullptr, nullptr, nullptr, m);
    // two sequential column passes: each pass's m-slice is L3-resident
    gather_p<<<NN, 128, 0, stream>>>(m, rowptr, elist, agg, 0);
    gather_p<<<NN, 128, 0, stream>>>(m, rowptr, elist, agg, 128);
    gru6<<<GRID_U, 256, 0, stream>>>(agg, h, wihBh, wihBl, whhBh, whhBl,
                                     bih, bhh, NJ_U, NPAN, m);
    float* t = h; h = m; m = t;   // gru wrote new h into old m
  }

  pool_g<<<NG, 256, 0, stream>>>(h, batch, bn2g, bn2b, bn2m, bn2v, gmean, gmax);
  fc1_k<<<(NG*H + 255)/256, 256, 0, stream>>>(gmean, gmax, fc1W, fc1b,
                                              bnfg, bnfb, bnfm, bnfv, fc1o);
  fc2_k<<<(NG*2 + 255)/256, 256, 0, stream>>>(fc1o, fc2W, fc2b, (float*)d_out);
}

// Round 8
// 2238.398 us; speedup vs baseline: 1.0698x; 1.0698x over previous
//
#include <hip/hip_runtime.h>
#include <cmath>

#define NN 100000
#define NE 1600000
#define NG 512
#define H 200
#define D 205
#define EPSV 1e-5f
#define SCAN_B 1024
#define KP 224    // weight (B-side) k-pitch, bf16, zero-padded
#define LPH 208   // node-buffer k-pitch (bf16 hi/lo pairs)

typedef __attribute__((ext_vector_type(8))) short short8v;
typedef __attribute__((ext_vector_type(4))) float f32x4;

#define MFMA16(a,b,c) __builtin_amdgcn_mfma_f32_16x16x32_bf16(a,b,c,0,0,0)

static __device__ __forceinline__ float sigm(float x){ return 1.0f/(1.0f+expf(-x)); }

// split fp32 -> bf16 hi (truncate) + bf16 lo (residual)
static __device__ __forceinline__ void split2(float x, unsigned short& h, unsigned short& l){
  unsigned xb = __float_as_uint(x);
  h = (unsigned short)(xb >> 16);
  float hf = __uint_as_float(xb & 0xffff0000u);
  l = (unsigned short)(__float_as_uint(x - hf) >> 16);
}

static __device__ __forceinline__ float uf(unsigned short u){
  return __uint_as_float(((unsigned)u) << 16);
}

static __device__ __forceinline__ void gload16(const void* src, void* dst){
  __builtin_amdgcn_global_load_lds(
      (const __attribute__((address_space(1))) unsigned int*)src,
      (__attribute__((address_space(3))) unsigned int*)dst, 16, 0, 0);
}

// ---------------- cvt fp32 [rows,C] -> hi/lo bf16 [rows,P], zero-padded ----------------
__global__ __launch_bounds__(256) void cvt_split(const float* __restrict__ in,
    unsigned short* __restrict__ hi, unsigned short* __restrict__ lo, int rows, int C, int P){
  long i = (long)blockIdx.x*256 + threadIdx.x;
  long tot = (long)rows*P;
  if (i >= tot) return;
  int r = (int)(i/P), c = (int)(i - (long)r*P);
  float v = (c < C) ? in[(size_t)r*C + c] : 0.f;
  unsigned short hh, ll; split2(v,hh,ll);
  hi[i] = hh; lo[i] = ll;
}

// ---------------- cvt + transpose: out[n][k]=in[k][n], [C,KP], zero-padded ----------------
__global__ __launch_bounds__(256) void cvt_tsplit(const float* __restrict__ in,
    unsigned short* __restrict__ hi, unsigned short* __restrict__ lo, int R, int C){
  int i = blockIdx.x*256 + threadIdx.x;
  if (i >= C*KP) return;
  int n = i/KP, k = i - n*KP;
  float v = (k < R) ? in[(size_t)k*C + n] : 0.f;
  unsigned short hh, ll; split2(v,hh,ll);
  hi[i] = hh; lo[i] = ll;
}

// ---------------- split-bf16 MFMA GEMM: C = (Ahi+Alo) @ (Bhi+Blo)^T, 3-term ----------------
// All operands pre-split bf16. LDS granule-major everywhere (2-way bank pattern, free).
// XCD-grouped 1-D grid (all nj j-tiles of a row panel on one XCD).
template<int EPIL>
__global__ __launch_bounds__(256) void mgemm(
    const unsigned short* __restrict__ Ahi, const unsigned short* __restrict__ Alo,
    const unsigned short* __restrict__ Bhi, const unsigned short* __restrict__ Blo,
    int M, int N, int nj, int npan,
    const float* __restrict__ bias,
    const float* __restrict__ bg, const float* __restrict__ bb,
    const float* __restrict__ bm, const float* __restrict__ bv,
    unsigned short* __restrict__ Chi, unsigned short* __restrict__ Clo)
{
  __shared__ __align__(16) char S[32768];   // regions: Ahi 0, Alo 8K, Bhi 16K, Blo 24K
  const int bid = blockIdx.x;
  const int xcd = bid & 7, sl = bid >> 3;
  const int pl = sl / nj, jj = sl - pl*nj;
  const int p = pl*8 + xcd;
  if (p >= npan) return;
  const int n0 = jj*128, r0 = p*128;
  const int tid = threadIdx.x, lane = tid & 63, wave = tid >> 6;
  const int wr = (wave>>1)*64, wc = (wave&1)*64;
  const int fr = lane & 15, fq = lane >> 4;
  f32x4 acc[4][4] = {};

  // 32 staging chunks of 1KB; this wave's 8. Descriptors hoisted (k0-invariant).
  const unsigned short* sp[8]; int sdst[8];
  #pragma unroll
  for (int i = 0; i < 8; ++i) {
    int g = wave + 4*i;                 // 0..31
    int region = g >> 3, c = g & 7, rowgrp = c >> 2, q = c & 3;
    int row = rowgrp*64 + lane;
    if (region < 2) {
      int rg = r0 + row; if (rg > M-1) rg = M-1;
      sp[i] = (region ? Alo : Ahi) + (size_t)rg*LPH + q*8;
    } else {
      int rg = n0 + row; if (rg > N-1) rg = N-1;
      sp[i] = ((region==3) ? Blo : Bhi) + (size_t)rg*KP + q*8;
    }
    sdst[i] = region*8192 + q*2048 + rowgrp*1024;
  }

  for (int k0 = 0; k0 < KP; k0 += 32) {
    #pragma unroll
    for (int i = 0; i < 8; ++i) gload16(sp[i] + k0, S + sdst[i]);
    __syncthreads();
    short8v ah[4], al[4], bh[4], bl[4];
    #pragma unroll
    for (int t = 0; t < 4; ++t) {
      int ra = (wr + t*16 + fr)*16, rb = (wc + t*16 + fr)*16;
      ah[t] = *(const short8v*)(S +     0 + fq*2048 + ra);
      al[t] = *(const short8v*)(S +  8192 + fq*2048 + ra);
      bh[t] = *(const short8v*)(S + 16384 + fq*2048 + rb);
      bl[t] = *(const short8v*)(S + 24576 + fq*2048 + rb);
    }
    #pragma unroll
    for (int i = 0; i < 4; ++i)
      #pragma unroll
      for (int j = 0; j < 4; ++j) {
        acc[i][j] = MFMA16(ah[i], bh[j], acc[i][j]);
        acc[i][j] = MFMA16(ah[i], bl[j], acc[i][j]);
        acc[i][j] = MFMA16(al[i], bh[j], acc[i][j]);
      }
    __syncthreads();
  }

  #pragma unroll
  for (int i = 0; i < 4; ++i)
    #pragma unroll
    for (int j = 0; j < 4; ++j)
      #pragma unroll
      for (int q = 0; q < 4; ++q) {
        int row = r0 + wr + i*16 + fq*4 + q;
        int col = n0 + wc + j*16 + fr;
        if (row < M && col < N) {
          float c = acc[i][j][q];
          if (EPIL) {
            c += bias[col];
            c = (c - bm[col]) * (bg[col] * rsqrtf(bv[col] + EPSV)) + bb[col];
            c = fmaxf(c, 0.f);
          }
          unsigned short hh, ll; split2(c, hh, ll);
          size_t o = (size_t)row*LPH + col;
          Chi[o] = hh; Clo[o] = ll;
        }
      }
}

// ---------------- fused GRU: 6 gate-GEMMs (MFMA, pre-split operands) + elementwise ----------------
__global__ __launch_bounds__(256) void gru6(
    const unsigned short* __restrict__ Ghi, const unsigned short* __restrict__ Glo, // agg pair
    const unsigned short* __restrict__ Hhi, const unsigned short* __restrict__ Hlo, // hprev pair
    const unsigned short* __restrict__ Wihh, const unsigned short* __restrict__ Wihl, // [600,KP]
    const unsigned short* __restrict__ Whhh, const unsigned short* __restrict__ Whhl,
    const float* __restrict__ bih, const float* __restrict__ bhh,
    int nj, int npan,
    unsigned short* __restrict__ Ohi, unsigned short* __restrict__ Olo)
{
  __shared__ __align__(16) char S[57344]; // Ghi 0, Glo 8K, Hhi 16K, Hlo 24K, Ws0 32K(12K), Ws1 44K(12K)
  const int bid = blockIdx.x;
  const int xcd = bid & 7, sl = bid >> 3;
  const int pl = sl / nj, jt = sl - pl*nj;
  const int p = pl*8 + xcd;
  if (p >= npan) return;
  const int j0 = jt*32, r0 = p*128;
  const int tid = threadIdx.x, lane = tid & 63, wave = tid >> 6;
  const int fr = lane & 15, fq = lane >> 4;
  f32x4 acc[6][2][2] = {};   // [gate][row-sub][col-sub]

  // 56 staging chunks; this wave's 14. Hoisted descriptors.
  const unsigned short* sp[14]; int sdst[14];
  #pragma unroll
  for (int i = 0; i < 14; ++i) {
    int g = wave + 4*i;                 // 0..55
    if (g < 32) {
      int region = g >> 3, c = g & 7, rowgrp = c >> 2, q = c & 3;
      int row = rowgrp*64 + lane;
      int rg = r0 + row; if (rg > NN-1) rg = NN-1;
      const unsigned short* base = (region==0)?Ghi:(region==1)?Glo:(region==2)?Hhi:Hlo;
      sp[i] = base + (size_t)rg*LPH + q*8;
      sdst[i] = region*8192 + q*2048 + rowgrp*1024;
    } else {
      int w = g - 32, comp = w/12, c = w - comp*12, rowgrp = c >> 2, q = c & 3;
      int R = rowgrp*64 + lane, gate = R>>5, jjj = R&31;
      int g3 = (gate >= 3) ? gate-3 : gate;
      int jcol = j0 + jjj; if (jcol > H-1) jcol = H-1;
      const unsigned short* base = (gate < 3) ? (comp ? Wihl : Wihh) : (comp ? Whhl : Whhh);
      sp[i] = base + (size_t)(g3*H + jcol)*KP + q*8;
      sdst[i] = 32768 + comp*12288 + q*3072 + rowgrp*1024;
    }
  }

  for (int k0 = 0; k0 < KP; k0 += 32) {
    #pragma unroll
    for (int i = 0; i < 14; ++i) gload16(sp[i] + k0, S + sdst[i]);
    __syncthreads();
    short8v gh[2], gl[2], hh[2], hl[2];
    #pragma unroll
    for (int t = 0; t < 2; ++t) {
      int ra = (wave*32 + t*16 + fr)*16;
      gh[t] = *(const short8v*)(S +     0 + fq*2048 + ra);
      gl[t] = *(const short8v*)(S +  8192 + fq*2048 + ra);
      hh[t] = *(const short8v*)(S + 16384 + fq*2048 + ra);
      hl[t] = *(const short8v*)(S + 24576 + fq*2048 + ra);
    }
    #pragma unroll
    for (int g = 0; g < 6; ++g) {
      const char* w0 = S + 32768 + fq*3072;
      const char* w1 = S + 45056 + fq*3072;
      short8v b0h = *(const short8v*)(w0 + (g*32      + fr)*16);
      short8v b1h = *(const short8v*)(w0 + (g*32 + 16 + fr)*16);
      short8v b0l = *(const short8v*)(w1 + (g*32      + fr)*16);
      short8v b1l = *(const short8v*)(w1 + (g*32 + 16 + fr)*16);
      #pragma unroll
      for (int t = 0; t < 2; ++t) {
        short8v a_h = (g < 3) ? gh[t] : hh[t];
        short8v a_l = (g < 3) ? gl[t] : hl[t];
        acc[g][t][0] = MFMA16(a_h, b0h, acc[g][t][0]);
        acc[g][t][0] = MFMA16(a_h, b0l, acc[g][t][0]);
        acc[g][t][0] = MFMA16(a_l, b0h, acc[g][t][0]);
        acc[g][t][1] = MFMA16(a_h, b1h, acc[g][t][1]);
        acc[g][t][1] = MFMA16(a_h, b1l, acc[g][t][1]);
        acc[g][t][1] = MFMA16(a_l, b1h, acc[g][t][1]);
      }
    }
    __syncthreads();
  }

  #pragma unroll
  for (int ct = 0; ct < 2; ++ct) {
    int j = j0 + ct*16 + fr;
    if (j >= H) continue;
    float br  = bih[j]     + bhh[j];
    float bz  = bih[H+j]   + bhh[H+j];
    float bin = bih[2*H+j], bhn = bhh[2*H+j];
    #pragma unroll
    for (int t = 0; t < 2; ++t)
      #pragma unroll
      for (int q = 0; q < 4; ++q) {
        int row = r0 + wave*32 + t*16 + fq*4 + q;
        if (row >= NN) continue;
        float ir = acc[0][t][ct][q], iz = acc[1][t][ct][q], inn = acc[2][t][ct][q];
        float hr = acc[3][t][ct][q], hz = acc[4][t][ct][q], hn  = acc[5][t][ct][q];
        float r = sigm(ir + hr + br);
        float z = sigm(iz + hz + bz);
        float n = tanhf(inn + bin + r*(hn + bhn));
        size_t o = (size_t)row*LPH + j;
        float ho = uf(Hhi[o]) + uf(Hlo[o]);
        unsigned short hh2, ll2; split2((1.f - z)*n + z*ho, hh2, ll2);
        Ohi[o] = hh2; Olo[o] = ll2;
      }
  }
}

// ---------------- CSR build ----------------
__global__ __launch_bounds__(256) void hist_k(const int* __restrict__ dst, int* __restrict__ deg){
  int e = blockIdx.x*256 + threadIdx.x;
  if (e < NE) atomicAdd(&deg[dst[e]], 1);
}

__global__ __launch_bounds__(256) void scan1_k(const int* __restrict__ deg, int* __restrict__ part,
                                               int* __restrict__ bsum, int n){
  __shared__ int lds[256];
  int t = threadIdx.x;
  int base = blockIdx.x * SCAN_B + t*4;
  int v[4]; int s = 0;
  #pragma unroll
  for (int q = 0; q < 4; ++q){ int idx = base+q; v[q] = (idx < n) ? deg[idx] : 0; s += v[q]; }
  lds[t] = s;
  __syncthreads();
  for (int off = 1; off < 256; off <<= 1){
    int val = 0;
    if (t >= off) val = lds[t-off];
    __syncthreads();
    if (t >= off) lds[t] += val;
    __syncthreads();
  }
  if (t == 255) bsum[blockIdx.x] = lds[255];
  int run = (t == 0) ? 0 : lds[t-1];
  #pragma unroll
  for (int q = 0; q < 4; ++q){ int idx = base+q; if (idx < n) part[idx] = run; run += v[q]; }
}

__global__ void scan2_k(int* __restrict__ bsum, int nb){
  __shared__ int lds[128];
  int t = threadIdx.x;
  int v = (t < nb) ? bsum[t] : 0;
  lds[t] = v;
  __syncthreads();
  for (int off = 1; off < 128; off <<= 1){
    int val = 0;
    if (t >= off) val = lds[t-off];
    __syncthreads();
    if (t >= off) lds[t] += val;
    __syncthreads();
  }
  if (t < nb) bsum[t] = (t == 0) ? 0 : lds[t-1];
}

__global__ __launch_bounds__(256) void scan3_k(const int* __restrict__ part, const int* __restrict__ bsum,
                                               int* __restrict__ rowptr, int* __restrict__ cpos, int n){
  int i = blockIdx.x*256 + threadIdx.x;
  if (i < n){
    int v = part[i] + bsum[i >> 10];
    rowptr[i] = v;
    cpos[i] = v;
  }
  if (i == 0) rowptr[n] = NE;
}

__global__ __launch_bounds__(256) void fill_k(const int* __restrict__ src, const int* __restrict__ dst,
                                              int* __restrict__ cpos, int* __restrict__ elist){
  int e = blockIdx.x*256 + threadIdx.x;
  if (e < NE){
    int p = atomicAdd(&cpos[dst[e]], 1);
    elist[p] = src[e];
  }
}

// ---------------- gather: agg[n] = sum m[src]; LDS-preloaded indices + 4-way ILP ----------------
__global__ __launch_bounds__(256) void gather_k(const unsigned short* __restrict__ mhi,
                                                const unsigned short* __restrict__ mlo,
                                                const int* __restrict__ rowptr,
                                                const int* __restrict__ elist,
                                                unsigned short* __restrict__ ahi,
                                                unsigned short* __restrict__ alo){
  __shared__ int sIdx[256];
  int n = blockIdx.x;
  int beg = rowptr[n], end = rowptr[n+1];
  int j = threadIdx.x;
  float a0=0.f, a1=0.f, a2=0.f, a3=0.f;
  for (int c0 = beg; c0 < end; c0 += 256){
    int cnt = min(256, end - c0);
    __syncthreads();
    if (threadIdx.x < cnt) sIdx[threadIdx.x] = elist[c0 + threadIdx.x];
    __syncthreads();
    if (j < H){
      int k = 0;
      for (; k + 4 <= cnt; k += 4){
        size_t s0 = (size_t)sIdx[k  ]*LPH + j;
        size_t s1 = (size_t)sIdx[k+1]*LPH + j;
        size_t s2 = (size_t)sIdx[k+2]*LPH + j;
        size_t s3 = (size_t)sIdx[k+3]*LPH + j;
        a0 += uf(mhi[s0]) + uf(mlo[s0]);
        a1 += uf(mhi[s1]) + uf(mlo[s1]);
        a2 += uf(mhi[s2]) + uf(mlo[s2]);
        a3 += uf(mhi[s3]) + uf(mlo[s3]);
      }
      for (; k < cnt; ++k){
        size_t s = (size_t)sIdx[k]*LPH + j;
        a0 += uf(mhi[s]) + uf(mlo[s]);
      }
    }
  }
  if (j < H){
    unsigned short hh, ll; split2((a0 + a1) + (a2 + a3), hh, ll);
    size_t o = (size_t)n*LPH + j;
    ahi[o] = hh; alo[o] = ll;
  }
}

// ---------------- pooling: one block per graph (batch sorted) ----------------
__global__ __launch_bounds__(256) void pool_g(
    const unsigned short* __restrict__ hhi, const unsigned short* __restrict__ hlo,
    const int* __restrict__ batch,
    const float* __restrict__ g2, const float* __restrict__ b2,
    const float* __restrict__ m2, const float* __restrict__ v2,
    float* __restrict__ gmean, float* __restrict__ gmax)
{
  int g = blockIdx.x;
  int lo = 0, hi = NN;
  while (lo < hi){ int mid = (lo+hi)>>1; if (batch[mid] < g) lo = mid+1; else hi = mid; }
  int lo2 = lo, hi2 = NN;
  while (lo2 < hi2){ int mid = (lo2+hi2)>>1; if (batch[mid] < g+1) lo2 = mid+1; else hi2 = mid; }
  int j = threadIdx.x;
  if (j >= H) return;
  float s = g2[j] * rsqrtf(v2[j] + EPSV);
  float mm = m2[j], bb = b2[j];
  float sum = 0.f, mx = 0.f;
  for (int n = lo; n < hi2; ++n){
    size_t o = (size_t)n*LPH + j;
    float hv = uf(hhi[o]) + uf(hlo[o]);
    float val = fmaxf((hv - mm)*s + bb, 0.f);
    sum += val;
    mx = fmaxf(mx, val);
  }
  int c = hi2 - lo;
  gmean[g*H + j] = (c > 0) ? sum/(float)c : 0.f;
  gmax [g*H + j] = mx;
}

// ---------------- fc1 + bnf + relu ----------------
__global__ __launch_bounds__(256) void fc1_k(
    const float* __restrict__ gmean, const float* __restrict__ gmax,
    const float* __restrict__ W,
    const float* __restrict__ bias,
    const float* __restrict__ fg, const float* __restrict__ fb,
    const float* __restrict__ fm, const float* __restrict__ fv,
    float* __restrict__ out)
{
  int tid = blockIdx.x*256 + threadIdx.x;
  if (tid >= NG*H) return;
  int g = tid / H, j = tid - g*H;
  const float* wr = W + j*2*H;
  float acc = bias[j];
  for (int k = 0; k < H; ++k) acc += gmean[g*H + k] * wr[k];
  for (int k = 0; k < H; ++k) acc += gmax[g*H + k] * wr[H + k];
  float s = fg[j] * rsqrtf(fv[j] + EPSV);
  acc = (acc - fm[j]) * s + fb[j];
  out[tid] = fmaxf(acc, 0.f);
}

__global__ void fc2_k(const float* __restrict__ in, const float* __restrict__ W,
                      const float* __restrict__ bias, float* __restrict__ out)
{
  int tid = blockIdx.x*256 + threadIdx.x;
  if (tid >= NG*2) return;
  int g = tid >> 1, c = tid & 1;
  float acc = bias[c];
  const float* wr = W + c*H;
  const float* xr = in + g*H;
  for (int k = 0; k < H; ++k) acc += xr[k]*wr[k];
  out[tid] = acc;
}

extern "C" void kernel_launch(void* const* d_in, const int* in_sizes, int n_in,
                              void* d_out, int out_size, void* d_ws, size_t ws_size,
                              hipStream_t stream)
{
  const float* x     = (const float*)d_in[0];
  const int*   eidx  = (const int*)d_in[1];
  const int*   batch = (const int*)d_in[2];
  const float* projW = (const float*)d_in[3];
  const float* projb = (const float*)d_in[4];
  const float* bn1g  = (const float*)d_in[5];
  const float* bn1b  = (const float*)d_in[6];
  const float* bn1m  = (const float*)d_in[7];
  const float* bn1v  = (const float*)d_in[8];
  const float* bn2g  = (const float*)d_in[9];
  const float* bn2b  = (const float*)d_in[10];
  const float* bn2m  = (const float*)d_in[11];
  const float* bn2v  = (const float*)d_in[12];
  const float* bnfg  = (const float*)d_in[13];
  const float* bnfb  = (const float*)d_in[14];
  const float* bnfm  = (const float*)d_in[15];
  const float* bnfv  = (const float*)d_in[16];
  const float* ggcW  = (const float*)d_in[17];
  const float* wih   = (const float*)d_in[18];
  const float* whh   = (const float*)d_in[19];
  const float* bih   = (const float*)d_in[20];
  const float* bhh   = (const float*)d_in[21];
  const float* fc1W  = (const float*)d_in[22];
  const float* fc1b  = (const float*)d_in[23];
  const float* fc2W  = (const float*)d_in[24];
  const float* fc2b  = (const float*)d_in[25];

  char* wsp = (char*)d_ws;
  auto alloc = [&](size_t nbytes) {
    char* p = wsp;
    wsp += ((nbytes + 255) / 256) * 256;
    return (void*)p;
  };
  // node-tensor bf16 hi/lo pairs, pitch LPH=208; xagg pair doubles as x-input then agg
  unsigned short* xaHi = (unsigned short*)alloc((size_t)NN*LPH*2);
  unsigned short* xaLo = (unsigned short*)alloc((size_t)NN*LPH*2);
  unsigned short* hHi  = (unsigned short*)alloc((size_t)NN*LPH*2);
  unsigned short* hLo  = (unsigned short*)alloc((size_t)NN*LPH*2);
  unsigned short* mHi  = (unsigned short*)alloc((size_t)NN*LPH*2);
  unsigned short* mLo  = (unsigned short*)alloc((size_t)NN*LPH*2);
  // weights (bf16 split, zero-padded to KP)
  unsigned short* pBh   = (unsigned short*)alloc((size_t)H*KP*2);
  unsigned short* pBl   = (unsigned short*)alloc((size_t)H*KP*2);
  unsigned short* wihBh = (unsigned short*)alloc((size_t)3*H*KP*2);
  unsigned short* wihBl = (unsigned short*)alloc((size_t)3*H*KP*2);
  unsigned short* whhBh = (unsigned short*)alloc((size_t)3*H*KP*2);
  unsigned short* whhBl = (unsigned short*)alloc((size_t)3*H*KP*2);
  unsigned short* gBh[3]; unsigned short* gBl[3];
  for (int i = 0; i < 3; ++i) {
    gBh[i] = (unsigned short*)alloc((size_t)H*KP*2);
    gBl[i] = (unsigned short*)alloc((size_t)H*KP*2);
  }
  float* gmean = (float*)alloc((size_t)NG*H*4);
  float* gmax  = (float*)alloc((size_t)NG*H*4);
  float* fc1o  = (float*)alloc((size_t)NG*H*4);
  const int NB = (NN + SCAN_B - 1) / SCAN_B;
  int* deg    = (int*)alloc((size_t)NN*4);
  int* part   = (int*)alloc((size_t)NN*4);
  int* bsum   = (int*)alloc((size_t)NB*4);
  int* rowptr = (int*)alloc((size_t)(NN+1)*4);
  int* cpos   = (int*)alloc((size_t)NN*4);
  int* elist  = (int*)alloc((size_t)NE*4);

  const int* srcp = eidx;
  const int* dstp = eidx + NE;

  // ---- CSR build (reused all 3 steps) ----
  hipMemsetAsync(deg, 0, (size_t)NN*4, stream);
  hist_k<<<(NE + 255)/256, 256, 0, stream>>>(dstp, deg);
  scan1_k<<<NB, 256, 0, stream>>>(deg, part, bsum, NN);
  scan2_k<<<1, 128, 0, stream>>>(bsum, NB);
  scan3_k<<<(NN + 255)/256, 256, 0, stream>>>(part, bsum, rowptr, cpos, NN);
  fill_k<<<(NE + 255)/256, 256, 0, stream>>>(srcp, dstp, cpos, elist);

  // ---- weight splits (pitch KP, zero-padded) ----
  cvt_split<<<(int)(((long)H*KP + 255)/256), 256, 0, stream>>>(projW, pBh, pBl, H, D, KP);
  cvt_split<<<(int)(((long)3*H*KP + 255)/256), 256, 0, stream>>>(wih, wihBh, wihBl, 3*H, H, KP);
  cvt_split<<<(int)(((long)3*H*KP + 255)/256), 256, 0, stream>>>(whh, whhBh, whhBl, 3*H, H, KP);
  for (int i = 0; i < 3; ++i)
    cvt_tsplit<<<(H*KP + 255)/256, 256, 0, stream>>>(ggcW + (size_t)i*H*H, gBh[i], gBl[i], H, H);

  // ---- x -> split pair (pitch LPH, zero-padded) ----
  cvt_split<<<(int)(((long)NN*LPH + 255)/256), 256, 0, stream>>>(x, xaHi, xaLo, NN, D, LPH);

  // XCD-grouped grids
  const int NPAN = (NN + 127)/128;            // 782
  const int PL8  = (NPAN + 7)/8;              // 98
  const int NJ_G = (H + 127)/128;             // 2
  const int NJ_U = (H + 31)/32;               // 7
  const int GRID_G = 8 * NJ_G * PL8;
  const int GRID_U = 8 * NJ_U * PL8;

  // proj + bn1 + relu : xpair -> hpair
  mgemm<1><<<GRID_G, 256, 0, stream>>>(xaHi, xaLo, pBh, pBl, NN, H, NJ_G, NPAN,
                                       projb, bn1g, bn1b, bn1m, bn1v, hHi, hLo);

  unsigned short *chHi = hHi, *chLo = hLo, *cmHi = mHi, *cmLo = mLo;
  for (int i = 0; i < 3; ++i) {
    mgemm<0><<<GRID_G, 256, 0, stream>>>(chHi, chLo, gBh[i], gBl[i], NN, H, NJ_G, NPAN,
                                         nullptr, nullptr, nullptr, nullptr, nullptr,
                                         cmHi, cmLo);
    gather_k<<<NN, 256, 0, stream>>>(cmHi, cmLo, rowptr, elist, xaHi, xaLo);
    gru6<<<GRID_U, 256, 0, stream>>>(xaHi, xaLo, chHi, chLo,
                                     wihBh, wihBl, whhBh, whhBl,
                                     bih, bhh, NJ_U, NPAN, cmHi, cmLo);
    unsigned short* t;
    t = chHi; chHi = cmHi; cmHi = t;
    t = chLo; chLo = cmLo; cmLo = t;
  }

  pool_g<<<NG, 256, 0, stream>>>(chHi, chLo, batch, bn2g, bn2b, bn2m, bn2v, gmean, gmax);
  fc1_k<<<(NG*H + 255)/256, 256, 0, stream>>>(gmean, gmax, fc1W, fc1b,
                                              bnfg, bnfb, bnfm, bnfv, fc1o);
  fc2_k<<<(NG*2 + 255)/256, 256, 0, stream>>>(fc1o, fc2W, fc2b, (float*)d_out);
}

// Round 9
// 2211.451 us; speedup vs baseline: 1.0828x; 1.0122x over previous
//
#include <hip/hip_runtime.h>
#include <cmath>

#define NN 100000
#define NE 1600000
#define NG 512
#define H 200
#define D 205
#define EPSV 1e-5f
#define SCAN_B 1024
#define KP 224    // weight (B-side) k-pitch, bf16, zero-padded
#define LPH 208   // node-buffer k-pitch (bf16 hi/lo pairs)

typedef __attribute__((ext_vector_type(8))) short short8v;
typedef __attribute__((ext_vector_type(4))) float f32x4;

#define MFMA16(a,b,c) __builtin_amdgcn_mfma_f32_16x16x32_bf16(a,b,c,0,0,0)

static __device__ __forceinline__ float sigm(float x){ return 1.0f/(1.0f+expf(-x)); }

// split fp32 -> bf16 hi (truncate) + bf16 lo (residual)
static __device__ __forceinline__ void split2(float x, unsigned short& h, unsigned short& l){
  unsigned xb = __float_as_uint(x);
  h = (unsigned short)(xb >> 16);
  float hf = __uint_as_float(xb & 0xffff0000u);
  l = (unsigned short)(__float_as_uint(x - hf) >> 16);
}

static __device__ __forceinline__ float uf(unsigned short u){
  return __uint_as_float(((unsigned)u) << 16);
}

static __device__ __forceinline__ void gload16(const void* src, void* dst){
  __builtin_amdgcn_global_load_lds(
      (const __attribute__((address_space(1))) unsigned int*)src,
      (__attribute__((address_space(3))) unsigned int*)dst, 16, 0, 0);
}

// ---------------- cvt fp32 [rows,C] -> hi/lo bf16 [rows,P], zero-padded ----------------
__global__ __launch_bounds__(256) void cvt_split(const float* __restrict__ in,
    unsigned short* __restrict__ hi, unsigned short* __restrict__ lo, int rows, int C, int P){
  long i = (long)blockIdx.x*256 + threadIdx.x;
  long tot = (long)rows*P;
  if (i >= tot) return;
  int r = (int)(i/P), c = (int)(i - (long)r*P);
  float v = (c < C) ? in[(size_t)r*C + c] : 0.f;
  unsigned short hh, ll; split2(v,hh,ll);
  hi[i] = hh; lo[i] = ll;
}

// ---------------- cvt + transpose: out[n][k]=in[k][n], [C,KP], zero-padded ----------------
__global__ __launch_bounds__(256) void cvt_tsplit(const float* __restrict__ in,
    unsigned short* __restrict__ hi, unsigned short* __restrict__ lo, int R, int C){
  int i = blockIdx.x*256 + threadIdx.x;
  if (i >= C*KP) return;
  int n = i/KP, k = i - n*KP;
  float v = (k < R) ? in[(size_t)k*C + n] : 0.f;
  unsigned short hh, ll; split2(v,hh,ll);
  hi[i] = hh; lo[i] = ll;
}

// ---------------- split-bf16 MFMA GEMM: C = (Ahi+Alo) @ (Bhi+Blo)^T, 3-term ----------------
// A fragments load DIRECTLY global->VGPR (L2-hot via XCD grouping); only B staged in LDS
// (16KB) -> high occupancy, ~1/4 the LDS traffic. Overreads past k=200 hit W zero-pad.
template<int EPIL>
__global__ __launch_bounds__(256) void mgemm(
    const unsigned short* __restrict__ Ahi, const unsigned short* __restrict__ Alo,
    const unsigned short* __restrict__ Bhi, const unsigned short* __restrict__ Blo,
    int M, int N, int nj, int npan,
    const float* __restrict__ bias,
    const float* __restrict__ bg, const float* __restrict__ bb,
    const float* __restrict__ bm, const float* __restrict__ bv,
    unsigned short* __restrict__ Chi, unsigned short* __restrict__ Clo)
{
  __shared__ __align__(16) char S[16384];   // Bhi 0..8K, Blo 8K..16K (granule-major)
  const int bid = blockIdx.x;
  const int xcd = bid & 7, sl = bid >> 3;
  const int pl = sl / nj, jj = sl - pl*nj;
  const int p = pl*8 + xcd;
  if (p >= npan) return;
  const int n0 = jj*128, r0 = p*128;
  const int tid = threadIdx.x, lane = tid & 63, wave = tid >> 6;
  const int wr = (wave>>1)*64, wc = (wave&1)*64;
  const int fr = lane & 15, fq = lane >> 4;
  f32x4 acc[4][4] = {};

  // B staging: 16 chunks of 1KB, 4 per wave (hoisted descriptors)
  const unsigned short* sp[4]; int sdst[4];
  #pragma unroll
  for (int i = 0; i < 4; ++i) {
    int g = wave + 4*i;                 // 0..15
    int region = g >> 3, c = g & 7, rowgrp = c >> 2, q = c & 3;
    int row = rowgrp*64 + lane;
    int rg = n0 + row; if (rg > N-1) rg = N-1;
    sp[i] = (region ? Blo : Bhi) + (size_t)rg*KP + q*8;
    sdst[i] = region*8192 + q*2048 + rowgrp*1024;
  }
  // A fragment element-offsets (k0-invariant)
  int arow[4];
  #pragma unroll
  for (int t = 0; t < 4; ++t) {
    int rg = r0 + wr + t*16 + fr; if (rg > M-1) rg = M-1;
    arow[t] = rg*LPH + fq*8;
  }

  for (int k0 = 0; k0 < KP; k0 += 32) {
    #pragma unroll
    for (int i = 0; i < 4; ++i) gload16(sp[i] + k0, S + sdst[i]);
    __syncthreads();
    short8v ah[4], al[4], bh[4], bl[4];
    #pragma unroll
    for (int t = 0; t < 4; ++t) {
      ah[t] = *(const short8v*)(Ahi + arow[t] + k0);
      al[t] = *(const short8v*)(Alo + arow[t] + k0);
      int rb = (wc + t*16 + fr)*16;
      bh[t] = *(const short8v*)(S +    0 + fq*2048 + rb);
      bl[t] = *(const short8v*)(S + 8192 + fq*2048 + rb);
    }
    #pragma unroll
    for (int i = 0; i < 4; ++i)
      #pragma unroll
      for (int j = 0; j < 4; ++j) {
        acc[i][j] = MFMA16(ah[i], bh[j], acc[i][j]);
        acc[i][j] = MFMA16(ah[i], bl[j], acc[i][j]);
        acc[i][j] = MFMA16(al[i], bh[j], acc[i][j]);
      }
    __syncthreads();
  }

  #pragma unroll
  for (int i = 0; i < 4; ++i)
    #pragma unroll
    for (int j = 0; j < 4; ++j)
      #pragma unroll
      for (int q = 0; q < 4; ++q) {
        int row = r0 + wr + i*16 + fq*4 + q;
        int col = n0 + wc + j*16 + fr;
        if (row < M && col < N) {
          float c = acc[i][j][q];
          if (EPIL) {
            c += bias[col];
            c = (c - bm[col]) * (bg[col] * rsqrtf(bv[col] + EPSV)) + bb[col];
            c = fmaxf(c, 0.f);
          }
          unsigned short hh, ll; split2(c, hh, ll);
          size_t o = (size_t)row*LPH + col;
          Chi[o] = hh; Clo[o] = ll;
        }
      }
}

// ---------------- fused GRU: 6 gate-GEMMs + elementwise; A direct-load, W in LDS ----------------
__global__ __launch_bounds__(256) void gru6(
    const unsigned short* __restrict__ Ghi, const unsigned short* __restrict__ Glo, // agg pair
    const unsigned short* __restrict__ Hhi, const unsigned short* __restrict__ Hlo, // hprev pair
    const unsigned short* __restrict__ Wihh, const unsigned short* __restrict__ Wihl, // [600,KP]
    const unsigned short* __restrict__ Whhh, const unsigned short* __restrict__ Whhl,
    const float* __restrict__ bih, const float* __restrict__ bhh,
    int nj, int npan,
    unsigned short* __restrict__ Ohi, unsigned short* __restrict__ Olo)
{
  __shared__ __align__(16) char S[24576];   // Ws0 0..12K, Ws1 12K..24K (granule-major)
  const int bid = blockIdx.x;
  const int xcd = bid & 7, sl = bid >> 3;
  const int pl = sl / nj, jt = sl - pl*nj;
  const int p = pl*8 + xcd;
  if (p >= npan) return;
  const int j0 = jt*32, r0 = p*128;
  const int tid = threadIdx.x, lane = tid & 63, wave = tid >> 6;
  const int fr = lane & 15, fq = lane >> 4;
  f32x4 acc[6][2][2] = {};   // [gate][row-sub][col-sub]

  // W staging: 24 chunks of 1KB, 6 per wave
  const unsigned short* sp[6]; int sdst[6];
  #pragma unroll
  for (int i = 0; i < 6; ++i) {
    int g = wave + 4*i;                 // 0..23
    int comp = g / 12, c = g - comp*12, rowgrp = c >> 2, q = c & 3;
    int R = rowgrp*64 + lane, gate = R>>5, jjj = R&31;
    int g3 = (gate >= 3) ? gate-3 : gate;
    int jcol = j0 + jjj; if (jcol > H-1) jcol = H-1;
    const unsigned short* base = (gate < 3) ? (comp ? Wihl : Wihh) : (comp ? Whhl : Whhh);
    sp[i] = base + (size_t)(g3*H + jcol)*KP + q*8;
    sdst[i] = comp*12288 + q*3072 + rowgrp*1024;
  }
  // A fragment element-offsets (k0-invariant)
  int arow[2];
  #pragma unroll
  for (int t = 0; t < 2; ++t) {
    int rg = r0 + wave*32 + t*16 + fr; if (rg > NN-1) rg = NN-1;
    arow[t] = rg*LPH + fq*8;
  }

  for (int k0 = 0; k0 < KP; k0 += 32) {
    #pragma unroll
    for (int i = 0; i < 6; ++i) gload16(sp[i] + k0, S + sdst[i]);
    __syncthreads();
    short8v gh[2], gl[2], hh[2], hl[2];
    #pragma unroll
    for (int t = 0; t < 2; ++t) {
      gh[t] = *(const short8v*)(Ghi + arow[t] + k0);
      gl[t] = *(const short8v*)(Glo + arow[t] + k0);
      hh[t] = *(const short8v*)(Hhi + arow[t] + k0);
      hl[t] = *(const short8v*)(Hlo + arow[t] + k0);
    }
    #pragma unroll
    for (int g = 0; g < 6; ++g) {
      const char* w0 = S +     0 + fq*3072;
      const char* w1 = S + 12288 + fq*3072;
      short8v b0h = *(const short8v*)(w0 + (g*32      + fr)*16);
      short8v b1h = *(const short8v*)(w0 + (g*32 + 16 + fr)*16);
      short8v b0l = *(const short8v*)(w1 + (g*32      + fr)*16);
      short8v b1l = *(const short8v*)(w1 + (g*32 + 16 + fr)*16);
      #pragma unroll
      for (int t = 0; t < 2; ++t) {
        short8v a_h = (g < 3) ? gh[t] : hh[t];
        short8v a_l = (g < 3) ? gl[t] : hl[t];
        acc[g][t][0] = MFMA16(a_h, b0h, acc[g][t][0]);
        acc[g][t][0] = MFMA16(a_h, b0l, acc[g][t][0]);
        acc[g][t][0] = MFMA16(a_l, b0h, acc[g][t][0]);
        acc[g][t][1] = MFMA16(a_h, b1h, acc[g][t][1]);
        acc[g][t][1] = MFMA16(a_h, b1l, acc[g][t][1]);
        acc[g][t][1] = MFMA16(a_l, b1h, acc[g][t][1]);
      }
    }
    __syncthreads();
  }

  #pragma unroll
  for (int ct = 0; ct < 2; ++ct) {
    int j = j0 + ct*16 + fr;
    if (j >= H) continue;
    float br  = bih[j]     + bhh[j];
    float bz  = bih[H+j]   + bhh[H+j];
    float bin = bih[2*H+j], bhn = bhh[2*H+j];
    #pragma unroll
    for (int t = 0; t < 2; ++t)
      #pragma unroll
      for (int q = 0; q < 4; ++q) {
        int row = r0 + wave*32 + t*16 + fq*4 + q;
        if (row >= NN) continue;
        float ir = acc[0][t][ct][q], iz = acc[1][t][ct][q], inn = acc[2][t][ct][q];
        float hr = acc[3][t][ct][q], hz = acc[4][t][ct][q], hn  = acc[5][t][ct][q];
        float r = sigm(ir + hr + br);
        float z = sigm(iz + hz + bz);
        float n = tanhf(inn + bin + r*(hn + bhn));
        size_t o = (size_t)row*LPH + j;
        float ho = uf(Hhi[o]) + uf(Hlo[o]);
        unsigned short hh2, ll2; split2((1.f - z)*n + z*ho, hh2, ll2);
        Ohi[o] = hh2; Olo[o] = ll2;
      }
  }
}

// ---------------- CSR build ----------------
__global__ __launch_bounds__(256) void hist_k(const int* __restrict__ dst, int* __restrict__ deg){
  int e = blockIdx.x*256 + threadIdx.x;
  if (e < NE) atomicAdd(&deg[dst[e]], 1);
}

__global__ __launch_bounds__(256) void scan1_k(const int* __restrict__ deg, int* __restrict__ part,
                                               int* __restrict__ bsum, int n){
  __shared__ int lds[256];
  int t = threadIdx.x;
  int base = blockIdx.x * SCAN_B + t*4;
  int v[4]; int s = 0;
  #pragma unroll
  for (int q = 0; q < 4; ++q){ int idx = base+q; v[q] = (idx < n) ? deg[idx] : 0; s += v[q]; }
  lds[t] = s;
  __syncthreads();
  for (int off = 1; off < 256; off <<= 1){
    int val = 0;
    if (t >= off) val = lds[t-off];
    __syncthreads();
    if (t >= off) lds[t] += val;
    __syncthreads();
  }
  if (t == 255) bsum[blockIdx.x] = lds[255];
  int run = (t == 0) ? 0 : lds[t-1];
  #pragma unroll
  for (int q = 0; q < 4; ++q){ int idx = base+q; if (idx < n) part[idx] = run; run += v[q]; }
}

__global__ void scan2_k(int* __restrict__ bsum, int nb){
  __shared__ int lds[128];
  int t = threadIdx.x;
  int v = (t < nb) ? bsum[t] : 0;
  lds[t] = v;
  __syncthreads();
  for (int off = 1; off < 128; off <<= 1){
    int val = 0;
    if (t >= off) val = lds[t-off];
    __syncthreads();
    if (t >= off) lds[t] += val;
    __syncthreads();
  }
  if (t < nb) bsum[t] = (t == 0) ? 0 : lds[t-1];
}

__global__ __launch_bounds__(256) void scan3_k(const int* __restrict__ part, const int* __restrict__ bsum,
                                               int* __restrict__ rowptr, int* __restrict__ cpos, int n){
  int i = blockIdx.x*256 + threadIdx.x;
  if (i < n){
    int v = part[i] + bsum[i >> 10];
    rowptr[i] = v;
    cpos[i] = v;
  }
  if (i == 0) rowptr[n] = NE;
}

__global__ __launch_bounds__(256) void fill_k(const int* __restrict__ src, const int* __restrict__ dst,
                                              int* __restrict__ cpos, int* __restrict__ elist){
  int e = blockIdx.x*256 + threadIdx.x;
  if (e < NE){
    int p = atomicAdd(&cpos[dst[e]], 1);
    elist[p] = src[e];
  }
}

// ---------------- gather: agg[n] = sum m[src]; LDS-preloaded indices + 4-way ILP ----------------
__global__ __launch_bounds__(256) void gather_k(const unsigned short* __restrict__ mhi,
                                                const unsigned short* __restrict__ mlo,
                                                const int* __restrict__ rowptr,
                                                const int* __restrict__ elist,
                                                unsigned short* __restrict__ ahi,
                                                unsigned short* __restrict__ alo){
  __shared__ int sIdx[256];
  int n = blockIdx.x;
  int beg = rowptr[n], end = rowptr[n+1];
  int j = threadIdx.x;
  float a0=0.f, a1=0.f, a2=0.f, a3=0.f;
  for (int c0 = beg; c0 < end; c0 += 256){
    int cnt = min(256, end - c0);
    __syncthreads();
    if (threadIdx.x < cnt) sIdx[threadIdx.x] = elist[c0 + threadIdx.x];
    __syncthreads();
    if (j < H){
      int k = 0;
      for (; k + 4 <= cnt; k += 4){
        size_t s0 = (size_t)sIdx[k  ]*LPH + j;
        size_t s1 = (size_t)sIdx[k+1]*LPH + j;
        size_t s2 = (size_t)sIdx[k+2]*LPH + j;
        size_t s3 = (size_t)sIdx[k+3]*LPH + j;
        a0 += uf(mhi[s0]) + uf(mlo[s0]);
        a1 += uf(mhi[s1]) + uf(mlo[s1]);
        a2 += uf(mhi[s2]) + uf(mlo[s2]);
        a3 += uf(mhi[s3]) + uf(mlo[s3]);
      }
      for (; k < cnt; ++k){
        size_t s = (size_t)sIdx[k]*LPH + j;
        a0 += uf(mhi[s]) + uf(mlo[s]);
      }
    }
  }
  if (j < H){
    unsigned short hh, ll; split2((a0 + a1) + (a2 + a3), hh, ll);
    size_t o = (size_t)n*LPH + j;
    ahi[o] = hh; alo[o] = ll;
  }
}

// ---------------- pooling: one block per graph (batch sorted) ----------------
__global__ __launch_bounds__(256) void pool_g(
    const unsigned short* __restrict__ hhi, const unsigned short* __restrict__ hlo,
    const int* __restrict__ batch,
    const float* __restrict__ g2, const float* __restrict__ b2,
    const float* __restrict__ m2, const float* __restrict__ v2,
    float* __restrict__ gmean, float* __restrict__ gmax)
{
  int g = blockIdx.x;
  int lo = 0, hi = NN;
  while (lo < hi){ int mid = (lo+hi)>>1; if (batch[mid] < g) lo = mid+1; else hi = mid; }
  int lo2 = lo, hi2 = NN;
  while (lo2 < hi2){ int mid = (lo2+hi2)>>1; if (batch[mid] < g+1) lo2 = mid+1; else hi2 = mid; }
  int j = threadIdx.x;
  if (j >= H) return;
  float s = g2[j] * rsqrtf(v2[j] + EPSV);
  float mm = m2[j], bb = b2[j];
  float sum = 0.f, mx = 0.f;
  for (int n = lo; n < hi2; ++n){
    size_t o = (size_t)n*LPH + j;
    float hv = uf(hhi[o]) + uf(hlo[o]);
    float val = fmaxf((hv - mm)*s + bb, 0.f);
    sum += val;
    mx = fmaxf(mx, val);
  }
  int c = hi2 - lo;
  gmean[g*H + j] = (c > 0) ? sum/(float)c : 0.f;
  gmax [g*H + j] = mx;
}

// ---------------- fc1 + bnf + relu ----------------
__global__ __launch_bounds__(256) void fc1_k(
    const float* __restrict__ gmean, const float* __restrict__ gmax,
    const float* __restrict__ W,
    const float* __restrict__ bias,
    const float* __restrict__ fg, const float* __restrict__ fb,
    const float* __restrict__ fm, const float* __restrict__ fv,
    float* __restrict__ out)
{
  int tid = blockIdx.x*256 + threadIdx.x;
  if (tid >= NG*H) return;
  int g = tid / H, j = tid - g*H;
  const float* wr = W + j*2*H;
  float acc = bias[j];
  for (int k = 0; k < H; ++k) acc += gmean[g*H + k] * wr[k];
  for (int k = 0; k < H; ++k) acc += gmax[g*H + k] * wr[H + k];
  float s = fg[j] * rsqrtf(fv[j] + EPSV);
  acc = (acc - fm[j]) * s + fb[j];
  out[tid] = fmaxf(acc, 0.f);
}

__global__ void fc2_k(const float* __restrict__ in, const float* __restrict__ W,
                      const float* __restrict__ bias, float* __restrict__ out)
{
  int tid = blockIdx.x*256 + threadIdx.x;
  if (tid >= NG*2) return;
  int g = tid >> 1, c = tid & 1;
  float acc = bias[c];
  const float* wr = W + c*H;
  const float* xr = in + g*H;
  for (int k = 0; k < H; ++k) acc += xr[k]*wr[k];
  out[tid] = acc;
}

extern "C" void kernel_launch(void* const* d_in, const int* in_sizes, int n_in,
                              void* d_out, int out_size, void* d_ws, size_t ws_size,
                              hipStream_t stream)
{
  const float* x     = (const float*)d_in[0];
  const int*   eidx  = (const int*)d_in[1];
  const int*   batch = (const int*)d_in[2];
  const float* projW = (const float*)d_in[3];
  const float* projb = (const float*)d_in[4];
  const float* bn1g  = (const float*)d_in[5];
  const float* bn1b  = (const float*)d_in[6];
  const float* bn1m  = (const float*)d_in[7];
  const float* bn1v  = (const float*)d_in[8];
  const float* bn2g  = (const float*)d_in[9];
  const float* bn2b  = (const float*)d_in[10];
  const float* bn2m  = (const float*)d_in[11];
  const float* bn2v  = (const float*)d_in[12];
  const float* bnfg  = (const float*)d_in[13];
  const float* bnfb  = (const float*)d_in[14];
  const float* bnfm  = (const float*)d_in[15];
  const float* bnfv  = (const float*)d_in[16];
  const float* ggcW  = (const float*)d_in[17];
  const float* wih   = (const float*)d_in[18];
  const float* whh   = (const float*)d_in[19];
  const float* bih   = (const float*)d_in[20];
  const float* bhh   = (const float*)d_in[21];
  const float* fc1W  = (const float*)d_in[22];
  const float* fc1b  = (const float*)d_in[23];
  const float* fc2W  = (const float*)d_in[24];
  const float* fc2b  = (const float*)d_in[25];

  char* wsp = (char*)d_ws;
  auto alloc = [&](size_t nbytes) {
    char* p = wsp;
    wsp += ((nbytes + 255) / 256) * 256;
    return (void*)p;
  };
  // node-tensor bf16 hi/lo pairs, pitch LPH=208; xa pair doubles as x-input then agg
  unsigned short* xaHi = (unsigned short*)alloc((size_t)NN*LPH*2);
  unsigned short* xaLo = (unsigned short*)alloc((size_t)NN*LPH*2);
  unsigned short* hHi  = (unsigned short*)alloc((size_t)NN*LPH*2);
  unsigned short* hLo  = (unsigned short*)alloc((size_t)NN*LPH*2);
  unsigned short* mHi  = (unsigned short*)alloc((size_t)NN*LPH*2);
  unsigned short* mLo  = (unsigned short*)alloc((size_t)NN*LPH*2);
  // weights (bf16 split, zero-padded to KP)
  unsigned short* pBh   = (unsigned short*)alloc((size_t)H*KP*2);
  unsigned short* pBl   = (unsigned short*)alloc((size_t)H*KP*2);
  unsigned short* wihBh = (unsigned short*)alloc((size_t)3*H*KP*2);
  unsigned short* wihBl = (unsigned short*)alloc((size_t)3*H*KP*2);
  unsigned short* whhBh = (unsigned short*)alloc((size_t)3*H*KP*2);
  unsigned short* whhBl = (unsigned short*)alloc((size_t)3*H*KP*2);
  unsigned short* gBh[3]; unsigned short* gBl[3];
  for (int i = 0; i < 3; ++i) {
    gBh[i] = (unsigned short*)alloc((size_t)H*KP*2);
    gBl[i] = (unsigned short*)alloc((size_t)H*KP*2);
  }
  float* gmean = (float*)alloc((size_t)NG*H*4);
  float* gmax  = (float*)alloc((size_t)NG*H*4);
  float* fc1o  = (float*)alloc((size_t)NG*H*4);
  const int NB = (NN + SCAN_B - 1) / SCAN_B;
  int* deg    = (int*)alloc((size_t)NN*4);
  int* part   = (int*)alloc((size_t)NN*4);
  int* bsum   = (int*)alloc((size_t)NB*4);
  int* rowptr = (int*)alloc((size_t)(NN+1)*4);
  int* cpos   = (int*)alloc((size_t)NN*4);
  int* elist  = (int*)alloc((size_t)NE*4);

  const int* srcp = eidx;
  const int* dstp = eidx + NE;

  // ---- CSR build (reused all 3 steps) ----
  hipMemsetAsync(deg, 0, (size_t)NN*4, stream);
  hist_k<<<(NE + 255)/256, 256, 0, stream>>>(dstp, deg);
  scan1_k<<<NB, 256, 0, stream>>>(deg, part, bsum, NN);
  scan2_k<<<1, 128, 0, stream>>>(bsum, NB);
  scan3_k<<<(NN + 255)/256, 256, 0, stream>>>(part, bsum, rowptr, cpos, NN);
  fill_k<<<(NE + 255)/256, 256, 0, stream>>>(srcp, dstp, cpos, elist);

  // ---- weight splits (pitch KP, zero-padded) ----
  cvt_split<<<(int)(((long)H*KP + 255)/256), 256, 0, stream>>>(projW, pBh, pBl, H, D, KP);
  cvt_split<<<(int)(((long)3*H*KP + 255)/256), 256, 0, stream>>>(wih, wihBh, wihBl, 3*H, H, KP);
  cvt_split<<<(int)(((long)3*H*KP + 255)/256), 256, 0, stream>>>(whh, whhBh, whhBl, 3*H, H, KP);
  for (int i = 0; i < 3; ++i)
    cvt_tsplit<<<(H*KP + 255)/256, 256, 0, stream>>>(ggcW + (size_t)i*H*H, gBh[i], gBl[i], H, H);

  // ---- x -> split pair (pitch LPH, zero-padded) ----
  cvt_split<<<(int)(((long)NN*LPH + 255)/256), 256, 0, stream>>>(x, xaHi, xaLo, NN, D, LPH);

  // XCD-grouped grids
  const int NPAN = (NN + 127)/128;            // 782
  const int PL8  = (NPAN + 7)/8;              // 98
  const int NJ_G = (H + 127)/128;             // 2
  const int NJ_U = (H + 31)/32;               // 7
  const int GRID_G = 8 * NJ_G * PL8;
  const int GRID_U = 8 * NJ_U * PL8;

  // proj + bn1 + relu : xpair -> hpair
  mgemm<1><<<GRID_G, 256, 0, stream>>>(xaHi, xaLo, pBh, pBl, NN, H, NJ_G, NPAN,
                                       projb, bn1g, bn1b, bn1m, bn1v, hHi, hLo);

  unsigned short *chHi = hHi, *chLo = hLo, *cmHi = mHi, *cmLo = mLo;
  for (int i = 0; i < 3; ++i) {
    mgemm<0><<<GRID_G, 256, 0, stream>>>(chHi, chLo, gBh[i], gBl[i], NN, H, NJ_G, NPAN,
                                         nullptr, nullptr, nullptr, nullptr, nullptr,
                                         cmHi, cmLo);
    gather_k<<<NN, 256, 0, stream>>>(cmHi, cmLo, rowptr, elist, xaHi, xaLo);
    gru6<<<GRID_U, 256, 0, stream>>>(xaHi, xaLo, chHi, chLo,
                                     wihBh, wihBl, whhBh, whhBl,
                                     bih, bhh, NJ_U, NPAN, cmHi, cmLo);
    unsigned short* t;
    t = chHi; chHi = cmHi; cmHi = t;
    t = chLo; chLo = cmLo; cmLo = t;
  }

  pool_g<<<NG, 256, 0, stream>>>(chHi, chLo, batch, bn2g, bn2b, bn2m, bn2v, gmean, gmax);
  fc1_k<<<(NG*H + 255)/256, 256, 0, stream>>>(gmean, gmax, fc1W, fc1b,
                                              bnfg, bnfb, bnfm, bnfv, fc1o);
  fc2_k<<<(NG*2 + 255)/256, 256, 0, stream>>>(fc1o, fc2W, fc2b, (float*)d_out);
}

// Round 12
// 2199.421 us; speedup vs baseline: 1.0888x; 1.0055x over previous
//
#include <hip/hip_runtime.h>
#include <cmath>

#define NN 100000
#define NE 1600000
#define NG 512
#define H 200
#define D 205
#define EPSV 1e-5f
#define SCAN_B 1024
#define KP 224    // weight (B-side) k-pitch, bf16, zero-padded
#define LPH 208   // node-buffer k-pitch (bf16 hi/lo pairs)

typedef __attribute__((ext_vector_type(8))) short short8v;
typedef __attribute__((ext_vector_type(4))) float f32x4;

#define MFMA16(a,b,c) __builtin_amdgcn_mfma_f32_16x16x32_bf16(a,b,c,0,0,0)

static __device__ __forceinline__ float sigm(float x){ return 1.0f/(1.0f+expf(-x)); }

// split fp32 -> bf16 hi (truncate) + bf16 lo (residual)
static __device__ __forceinline__ void split2(float x, unsigned short& h, unsigned short& l){
  unsigned xb = __float_as_uint(x);
  h = (unsigned short)(xb >> 16);
  float hf = __uint_as_float(xb & 0xffff0000u);
  l = (unsigned short)(__float_as_uint(x - hf) >> 16);
}

static __device__ __forceinline__ float uf(unsigned short u){
  return __uint_as_float(((unsigned)u) << 16);
}

static __device__ __forceinline__ void gload16(const void* src, void* dst){
  __builtin_amdgcn_global_load_lds(
      (const __attribute__((address_space(1))) unsigned int*)src,
      (__attribute__((address_space(3))) unsigned int*)dst, 16, 0, 0);
}

// ---------------- cvt fp32 [rows,C] -> hi/lo bf16 [rows,P], zero-padded ----------------
__global__ __launch_bounds__(256) void cvt_split(const float* __restrict__ in,
    unsigned short* __restrict__ hi, unsigned short* __restrict__ lo, int rows, int C, int P){
  long i = (long)blockIdx.x*256 + threadIdx.x;
  long tot = (long)rows*P;
  if (i >= tot) return;
  int r = (int)(i/P), c = (int)(i - (long)r*P);
  float v = (c < C) ? in[(size_t)r*C + c] : 0.f;
  unsigned short hh, ll; split2(v,hh,ll);
  hi[i] = hh; lo[i] = ll;
}

// ---------------- cvt + transpose: out[n][k]=in[k][n], [C,KP], zero-padded ----------------
__global__ __launch_bounds__(256) void cvt_tsplit(const float* __restrict__ in,
    unsigned short* __restrict__ hi, unsigned short* __restrict__ lo, int R, int C){
  int i = blockIdx.x*256 + threadIdx.x;
  if (i >= C*KP) return;
  int n = i/KP, k = i - n*KP;
  float v = (k < R) ? in[(size_t)k*C + n] : 0.f;
  unsigned short hh, ll; split2(v,hh,ll);
  hi[i] = hh; lo[i] = ll;
}

// ---------------- split-bf16 MFMA GEMM: C = (Ahi+Alo) @ (Bhi+Blo)^T, 3-term ----------------
// A fragments load DIRECTLY global->VGPR (L2-hot via XCD grouping); only B staged in LDS
// (16KB) -> high occupancy, ~1/4 the LDS traffic. Overreads past k=200 hit W zero-pad.
template<int EPIL>
__global__ __launch_bounds__(256) void mgemm(
    const unsigned short* __restrict__ Ahi, const unsigned short* __restrict__ Alo,
    const unsigned short* __restrict__ Bhi, const unsigned short* __restrict__ Blo,
    int M, int N, int nj, int npan,
    const float* __restrict__ bias,
    const float* __restrict__ bg, const float* __restrict__ bb,
    const float* __restrict__ bm, const float* __restrict__ bv,
    unsigned short* __restrict__ Chi, unsigned short* __restrict__ Clo)
{
  __shared__ __align__(16) char S[16384];   // Bhi 0..8K, Blo 8K..16K (granule-major)
  const int bid = blockIdx.x;
  const int xcd = bid & 7, sl = bid >> 3;
  const int pl = sl / nj, jj = sl - pl*nj;
  const int p = pl*8 + xcd;
  if (p >= npan) return;
  const int n0 = jj*128, r0 = p*128;
  const int tid = threadIdx.x, lane = tid & 63, wave = tid >> 6;
  const int wr = (wave>>1)*64, wc = (wave&1)*64;
  const int fr = lane & 15, fq = lane >> 4;
  f32x4 acc[4][4] = {};

  // B staging: 16 chunks of 1KB, 4 per wave (hoisted descriptors)
  const unsigned short* sp[4]; int sdst[4];
  #pragma unroll
  for (int i = 0; i < 4; ++i) {
    int g = wave + 4*i;                 // 0..15
    int region = g >> 3, c = g & 7, rowgrp = c >> 2, q = c & 3;
    int row = rowgrp*64 + lane;
    int rg = n0 + row; if (rg > N-1) rg = N-1;
    sp[i] = (region ? Blo : Bhi) + (size_t)rg*KP + q*8;
    sdst[i] = region*8192 + q*2048 + rowgrp*1024;
  }
  // A fragment element-offsets (k0-invariant)
  int arow[4];
  #pragma unroll
  for (int t = 0; t < 4; ++t) {
    int rg = r0 + wr + t*16 + fr; if (rg > M-1) rg = M-1;
    arow[t] = rg*LPH + fq*8;
  }

  for (int k0 = 0; k0 < KP; k0 += 32) {
    #pragma unroll
    for (int i = 0; i < 4; ++i) gload16(sp[i] + k0, S + sdst[i]);
    __syncthreads();
    short8v ah[4], al[4], bh[4], bl[4];
    #pragma unroll
    for (int t = 0; t < 4; ++t) {
      ah[t] = *(const short8v*)(Ahi + arow[t] + k0);
      al[t] = *(const short8v*)(Alo + arow[t] + k0);
      int rb = (wc + t*16 + fr)*16;
      bh[t] = *(const short8v*)(S +    0 + fq*2048 + rb);
      bl[t] = *(const short8v*)(S + 8192 + fq*2048 + rb);
    }
    #pragma unroll
    for (int i = 0; i < 4; ++i)
      #pragma unroll
      for (int j = 0; j < 4; ++j) {
        acc[i][j] = MFMA16(ah[i], bh[j], acc[i][j]);
        acc[i][j] = MFMA16(ah[i], bl[j], acc[i][j]);
        acc[i][j] = MFMA16(al[i], bh[j], acc[i][j]);
      }
    __syncthreads();
  }

  #pragma unroll
  for (int i = 0; i < 4; ++i)
    #pragma unroll
    for (int j = 0; j < 4; ++j)
      #pragma unroll
      for (int q = 0; q < 4; ++q) {
        int row = r0 + wr + i*16 + fq*4 + q;
        int col = n0 + wc + j*16 + fr;
        if (row < M && col < N) {
          float c = acc[i][j][q];
          if (EPIL) {
            c += bias[col];
            c = (c - bm[col]) * (bg[col] * rsqrtf(bv[col] + EPSV)) + bb[col];
            c = fmaxf(c, 0.f);
          }
          unsigned short hh, ll; split2(c, hh, ll);
          size_t o = (size_t)row*LPH + col;
          Chi[o] = hh; Clo[o] = ll;
        }
      }
}

// ---------------- fused GRU: 4-accumulator form (r,z input+hidden share an acc) ----------
// ONLY change vs round-9: acc[6] -> acc[4] (frees 32 AGPRs) + launch_bounds(256,3).
// A direct global->VGPR, W in LDS single buffer, __syncthreads structure (proven).
__global__ __launch_bounds__(256, 3) void gru6(
    const unsigned short* __restrict__ Ghi, const unsigned short* __restrict__ Glo,
    const unsigned short* __restrict__ Hhi, const unsigned short* __restrict__ Hlo,
    const unsigned short* __restrict__ Wihh, const unsigned short* __restrict__ Wihl,
    const unsigned short* __restrict__ Whhh, const unsigned short* __restrict__ Whhl,
    const float* __restrict__ bih, const float* __restrict__ bhh,
    int nj, int npan,
    unsigned short* __restrict__ Ohi, unsigned short* __restrict__ Olo)
{
  __shared__ __align__(16) char S[24576];   // Ws0 0..12K, Ws1 12K..24K (granule-major)
  const int bid = blockIdx.x;
  const int xcd = bid & 7, sl = bid >> 3;
  const int pl = sl / nj, jt = sl - pl*nj;
  const int p = pl*8 + xcd;
  if (p >= npan) return;
  const int j0 = jt*32, r0 = p*128;
  const int tid = threadIdx.x, lane = tid & 63, wave = tid >> 6;
  const int fr = lane & 15, fq = lane >> 4;
  f32x4 acc[4][2][2] = {};   // [0]=r(i+h), [1]=z(i+h), [2]=n-in, [3]=n-hid

  // W staging: 24 chunks of 1KB, 6 per wave
  const unsigned short* sp[6]; int sdst[6];
  #pragma unroll
  for (int i = 0; i < 6; ++i) {
    int g = wave + 4*i;                 // 0..23
    int comp = g / 12, c = g - comp*12, rowgrp = c >> 2, q = c & 3;
    int R = rowgrp*64 + lane, gate = R>>5, jjj = R&31;
    int g3 = (gate >= 3) ? gate-3 : gate;
    int jcol = j0 + jjj; if (jcol > H-1) jcol = H-1;
    const unsigned short* base = (gate < 3) ? (comp ? Wihl : Wihh) : (comp ? Whhl : Whhh);
    sp[i] = base + (size_t)(g3*H + jcol)*KP + q*8;
    sdst[i] = comp*12288 + q*3072 + rowgrp*1024;
  }
  // A fragment element-offsets (k0-invariant)
  int arow[2];
  #pragma unroll
  for (int t = 0; t < 2; ++t) {
    int rg = r0 + wave*32 + t*16 + fr; if (rg > NN-1) rg = NN-1;
    arow[t] = rg*LPH + fq*8;
  }

  for (int k0 = 0; k0 < KP; k0 += 32) {
    #pragma unroll
    for (int i = 0; i < 6; ++i) gload16(sp[i] + k0, S + sdst[i]);
    __syncthreads();
    short8v A[4][2];   // [comp: g-hi, g-lo, h-hi, h-lo][t]
    #pragma unroll
    for (int t = 0; t < 2; ++t) {
      A[0][t] = *(const short8v*)(Ghi + arow[t] + k0);
      A[1][t] = *(const short8v*)(Glo + arow[t] + k0);
      A[2][t] = *(const short8v*)(Hhi + arow[t] + k0);
      A[3][t] = *(const short8v*)(Hlo + arow[t] + k0);
    }
    #pragma unroll
    for (int g = 0; g < 6; ++g) {
      const char* w0 = S +     0 + fq*3072;
      const char* w1 = S + 12288 + fq*3072;
      short8v b0h = *(const short8v*)(w0 + (g*32      + fr)*16);
      short8v b1h = *(const short8v*)(w0 + (g*32 + 16 + fr)*16);
      short8v b0l = *(const short8v*)(w1 + (g*32      + fr)*16);
      short8v b1l = *(const short8v*)(w1 + (g*32 + 16 + fr)*16);
      const int ai = (g < 3) ? 0 : 2;               // input path vs hidden path
      const int ac = (g == 5) ? 3 : (g % 3);        // r,z shared; n-in=2, n-hid=3
      #pragma unroll
      for (int t = 0; t < 2; ++t) {
        acc[ac][t][0] = MFMA16(A[ai][t],   b0h, acc[ac][t][0]);
        acc[ac][t][0] = MFMA16(A[ai][t],   b0l, acc[ac][t][0]);
        acc[ac][t][0] = MFMA16(A[ai+1][t], b0h, acc[ac][t][0]);
        acc[ac][t][1] = MFMA16(A[ai][t],   b1h, acc[ac][t][1]);
        acc[ac][t][1] = MFMA16(A[ai][t],   b1l, acc[ac][t][1]);
        acc[ac][t][1] = MFMA16(A[ai+1][t], b1h, acc[ac][t][1]);
      }
    }
    __syncthreads();
  }

  #pragma unroll
  for (int ct = 0; ct < 2; ++ct) {
    int j = j0 + ct*16 + fr;
    if (j >= H) continue;
    float br  = bih[j]     + bhh[j];
    float bz  = bih[H+j]   + bhh[H+j];
    float bin = bih[2*H+j], bhn = bhh[2*H+j];
    #pragma unroll
    for (int t = 0; t < 2; ++t)
      #pragma unroll
      for (int q = 0; q < 4; ++q) {
        int row = r0 + wave*32 + t*16 + fq*4 + q;
        if (row >= NN) continue;
        float rv = sigm(acc[0][t][ct][q] + br);
        float zv = sigm(acc[1][t][ct][q] + bz);
        float nv = tanhf(acc[2][t][ct][q] + bin + rv*(acc[3][t][ct][q] + bhn));
        size_t o = (size_t)row*LPH + j;
        float ho = uf(Hhi[o]) + uf(Hlo[o]);
        unsigned short hh2, ll2; split2((1.f - zv)*nv + zv*ho, hh2, ll2);
        Ohi[o] = hh2; Olo[o] = ll2;
      }
  }
}

// ---------------- CSR build ----------------
__global__ __launch_bounds__(256) void hist_k(const int* __restrict__ dst, int* __restrict__ deg){
  int e = blockIdx.x*256 + threadIdx.x;
  if (e < NE) atomicAdd(&deg[dst[e]], 1);
}

__global__ __launch_bounds__(256) void scan1_k(const int* __restrict__ deg, int* __restrict__ part,
                                               int* __restrict__ bsum, int n){
  __shared__ int lds[256];
  int t = threadIdx.x;
  int base = blockIdx.x * SCAN_B + t*4;
  int v[4]; int s = 0;
  #pragma unroll
  for (int q = 0; q < 4; ++q){ int idx = base+q; v[q] = (idx < n) ? deg[idx] : 0; s += v[q]; }
  lds[t] = s;
  __syncthreads();
  for (int off = 1; off < 256; off <<= 1){
    int val = 0;
    if (t >= off) val = lds[t-off];
    __syncthreads();
    if (t >= off) lds[t] += val;
    __syncthreads();
  }
  if (t == 255) bsum[blockIdx.x] = lds[255];
  int run = (t == 0) ? 0 : lds[t-1];
  #pragma unroll
  for (int q = 0; q < 4; ++q){ int idx = base+q; if (idx < n) part[idx] = run; run += v[q]; }
}

__global__ void scan2_k(int* __restrict__ bsum, int nb){
  __shared__ int lds[128];
  int t = threadIdx.x;
  int v = (t < nb) ? bsum[t] : 0;
  lds[t] = v;
  __syncthreads();
  for (int off = 1; off < 128; off <<= 1){
    int val = 0;
    if (t >= off) val = lds[t-off];
    __syncthreads();
    if (t >= off) lds[t] += val;
    __syncthreads();
  }
  if (t < nb) bsum[t] = (t == 0) ? 0 : lds[t-1];
}

__global__ __launch_bounds__(256) void scan3_k(const int* __restrict__ part, const int* __restrict__ bsum,
                                               int* __restrict__ rowptr, int* __restrict__ cpos, int n){
  int i = blockIdx.x*256 + threadIdx.x;
  if (i < n){
    int v = part[i] + bsum[i >> 10];
    rowptr[i] = v;
    cpos[i] = v;
  }
  if (i == 0) rowptr[n] = NE;
}

__global__ __launch_bounds__(256) void fill_k(const int* __restrict__ src, const int* __restrict__ dst,
                                              int* __restrict__ cpos, int* __restrict__ elist){
  int e = blockIdx.x*256 + threadIdx.x;
  if (e < NE){
    int p = atomicAdd(&cpos[dst[e]], 1);
    elist[p] = src[e];
  }
}

// ---------------- gather: agg[n] = sum m[src]; LDS-preloaded indices + 4-way ILP ----------------
__global__ __launch_bounds__(256) void gather_k(const unsigned short* __restrict__ mhi,
                                                const unsigned short* __restrict__ mlo,
                                                const int* __restrict__ rowptr,
                                                const int* __restrict__ elist,
                                                unsigned short* __restrict__ ahi,
                                                unsigned short* __restrict__ alo){
  __shared__ int sIdx[256];
  int n = blockIdx.x;
  int beg = rowptr[n], end = rowptr[n+1];
  int j = threadIdx.x;
  float a0=0.f, a1=0.f, a2=0.f, a3=0.f;
  for (int c0 = beg; c0 < end; c0 += 256){
    int cnt = min(256, end - c0);
    __syncthreads();
    if (threadIdx.x < cnt) sIdx[threadIdx.x] = elist[c0 + threadIdx.x];
    __syncthreads();
    if (j < H){
      int k = 0;
      for (; k + 4 <= cnt; k += 4){
        size_t s0 = (size_t)sIdx[k  ]*LPH + j;
        size_t s1 = (size_t)sIdx[k+1]*LPH + j;
        size_t s2 = (size_t)sIdx[k+2]*LPH + j;
        size_t s3 = (size_t)sIdx[k+3]*LPH + j;
        a0 += uf(mhi[s0]) + uf(mlo[s0]);
        a1 += uf(mhi[s1]) + uf(mlo[s1]);
        a2 += uf(mhi[s2]) + uf(mlo[s2]);
        a3 += uf(mhi[s3]) + uf(mlo[s3]);
      }
      for (; k < cnt; ++k){
        size_t s = (size_t)sIdx[k]*LPH + j;
        a0 += uf(mhi[s]) + uf(mlo[s]);
      }
    }
  }
  if (j < H){
    unsigned short hh, ll; split2((a0 + a1) + (a2 + a3), hh, ll);
    size_t o = (size_t)n*LPH + j;
    ahi[o] = hh; alo[o] = ll;
  }
}

// ---------------- pooling: one block per graph (batch sorted) ----------------
__global__ __launch_bounds__(256) void pool_g(
    const unsigned short* __restrict__ hhi, const unsigned short* __restrict__ hlo,
    const int* __restrict__ batch,
    const float* __restrict__ g2, const float* __restrict__ b2,
    const float* __restrict__ m2, const float* __restrict__ v2,
    float* __restrict__ gmean, float* __restrict__ gmax)
{
  int g = blockIdx.x;
  int lo = 0, hi = NN;
  while (lo < hi){ int mid = (lo+hi)>>1; if (batch[mid] < g) lo = mid+1; else hi = mid; }
  int lo2 = lo, hi2 = NN;
  while (lo2 < hi2){ int mid = (lo2+hi2)>>1; if (batch[mid] < g+1) lo2 = mid+1; else hi2 = mid; }
  int j = threadIdx.x;
  if (j >= H) return;
  float s = g2[j] * rsqrtf(v2[j] + EPSV);
  float mm = m2[j], bb = b2[j];
  float sum = 0.f, mx = 0.f;
  for (int n = lo; n < hi2; ++n){
    size_t o = (size_t)n*LPH + j;
    float hv = uf(hhi[o]) + uf(hlo[o]);
    float val = fmaxf((hv - mm)*s + bb, 0.f);
    sum += val;
    mx = fmaxf(mx, val);
  }
  int c = hi2 - lo;
  gmean[g*H + j] = (c > 0) ? sum/(float)c : 0.f;
  gmax [g*H + j] = mx;
}

// ---------------- fc1 + bnf + relu ----------------
__global__ __launch_bounds__(256) void fc1_k(
    const float* __restrict__ gmean, const float* __restrict__ gmax,
    const float* __restrict__ W,
    const float* __restrict__ bias,
    const float* __restrict__ fg, const float* __restrict__ fb,
    const float* __restrict__ fm, const float* __restrict__ fv,
    float* __restrict__ out)
{
  int tid = blockIdx.x*256 + threadIdx.x;
  if (tid >= NG*H) return;
  int g = tid / H, j = tid - g*H;
  const float* wr = W + j*2*H;
  float acc = bias[j];
  for (int k = 0; k < H; ++k) acc += gmean[g*H + k] * wr[k];
  for (int k = 0; k < H; ++k) acc += gmax[g*H + k] * wr[H + k];
  float s = fg[j] * rsqrtf(fv[j] + EPSV);
  acc = (acc - fm[j]) * s + fb[j];
  out[tid] = fmaxf(acc, 0.f);
}

__global__ void fc2_k(const float* __restrict__ in, const float* __restrict__ W,
                      const float* __restrict__ bias, float* __restrict__ out)
{
  int tid = blockIdx.x*256 + threadIdx.x;
  if (tid >= NG*2) return;
  int g = tid >> 1, c = tid & 1;
  float acc = bias[c];
  const float* wr = W + c*H;
  const float* xr = in + g*H;
  for (int k = 0; k < H; ++k) acc += xr[k]*wr[k];
  out[tid] = acc;
}

extern "C" void kernel_launch(void* const* d_in, const int* in_sizes, int n_in,
                              void* d_out, int out_size, void* d_ws, size_t ws_size,
                              hipStream_t stream)
{
  const float* x     = (const float*)d_in[0];
  const int*   eidx  = (const int*)d_in[1];
  const int*   batch = (const int*)d_in[2];
  const float* projW = (const float*)d_in[3];
  const float* projb = (const float*)d_in[4];
  const float* bn1g  = (const float*)d_in[5];
  const float* bn1b  = (const float*)d_in[6];
  const float* bn1m  = (const float*)d_in[7];
  const float* bn1v  = (const float*)d_in[8];
  const float* bn2g  = (const float*)d_in[9];
  const float* bn2b  = (const float*)d_in[10];
  const float* bn2m  = (const float*)d_in[11];
  const float* bn2v  = (const float*)d_in[12];
  const float* bnfg  = (const float*)d_in[13];
  const float* bnfb  = (const float*)d_in[14];
  const float* bnfm  = (const float*)d_in[15];
  const float* bnfv  = (const float*)d_in[16];
  const float* ggcW  = (const float*)d_in[17];
  const float* wih   = (const float*)d_in[18];
  const float* whh   = (const float*)d_in[19];
  const float* bih   = (const float*)d_in[20];
  const float* bhh   = (const float*)d_in[21];
  const float* fc1W  = (const float*)d_in[22];
  const float* fc1b  = (const float*)d_in[23];
  const float* fc2W  = (const float*)d_in[24];
  const float* fc2b  = (const float*)d_in[25];

  char* wsp = (char*)d_ws;
  auto alloc = [&](size_t nbytes) {
    char* p = wsp;
    wsp += ((nbytes + 255) / 256) * 256;
    return (void*)p;
  };
  // node-tensor bf16 hi/lo pairs, pitch LPH=208; xa pair doubles as x-input then agg
  unsigned short* xaHi = (unsigned short*)alloc((size_t)NN*LPH*2);
  unsigned short* xaLo = (unsigned short*)alloc((size_t)NN*LPH*2);
  unsigned short* hHi  = (unsigned short*)alloc((size_t)NN*LPH*2);
  unsigned short* hLo  = (unsigned short*)alloc((size_t)NN*LPH*2);
  unsigned short* mHi  = (unsigned short*)alloc((size_t)NN*LPH*2);
  unsigned short* mLo  = (unsigned short*)alloc((size_t)NN*LPH*2);
  // weights (bf16 split, zero-padded to KP)
  unsigned short* pBh   = (unsigned short*)alloc((size_t)H*KP*2);
  unsigned short* pBl   = (unsigned short*)alloc((size_t)H*KP*2);
  unsigned short* wihBh = (unsigned short*)alloc((size_t)3*H*KP*2);
  unsigned short* wihBl = (unsigned short*)alloc((size_t)3*H*KP*2);
  unsigned short* whhBh = (unsigned short*)alloc((size_t)3*H*KP*2);
  unsigned short* whhBl = (unsigned short*)alloc((size_t)3*H*KP*2);
  unsigned short* gBh[3]; unsigned short* gBl[3];
  for (int i = 0; i < 3; ++i) {
    gBh[i] = (unsigned short*)alloc((size_t)H*KP*2);
    gBl[i] = (unsigned short*)alloc((size_t)H*KP*2);
  }
  float* gmean = (float*)alloc((size_t)NG*H*4);
  float* gmax  = (float*)alloc((size_t)NG*H*4);
  float* fc1o  = (float*)alloc((size_t)NG*H*4);
  const int NB = (NN + SCAN_B - 1) / SCAN_B;
  int* deg    = (int*)alloc((size_t)NN*4);
  int* part   = (int*)alloc((size_t)NN*4);
  int* bsum   = (int*)alloc((size_t)NB*4);
  int* rowptr = (int*)alloc((size_t)(NN+1)*4);
  int* cpos   = (int*)alloc((size_t)NN*4);
  int* elist  = (int*)alloc((size_t)NE*4);

  const int* srcp = eidx;
  const int* dstp = eidx + NE;

  // ---- CSR build (reused all 3 steps) ----
  hipMemsetAsync(deg, 0, (size_t)NN*4, stream);
  hist_k<<<(NE + 255)/256, 256, 0, stream>>>(dstp, deg);
  scan1_k<<<NB, 256, 0, stream>>>(deg, part, bsum, NN);
  scan2_k<<<1, 128, 0, stream>>>(bsum, NB);
  scan3_k<<<(NN + 255)/256, 256, 0, stream>>>(part, bsum, rowptr, cpos, NN);
  fill_k<<<(NE + 255)/256, 256, 0, stream>>>(srcp, dstp, cpos, elist);

  // ---- weight splits (pitch KP, zero-padded) ----
  cvt_split<<<(int)(((long)H*KP + 255)/256), 256, 0, stream>>>(projW, pBh, pBl, H, D, KP);
  cvt_split<<<(int)(((long)3*H*KP + 255)/256), 256, 0, stream>>>(wih, wihBh, wihBl, 3*H, H, KP);
  cvt_split<<<(int)(((long)3*H*KP + 255)/256), 256, 0, stream>>>(whh, whhBh, whhBl, 3*H, H, KP);
  for (int i = 0; i < 3; ++i)
    cvt_tsplit<<<(H*KP + 255)/256, 256, 0, stream>>>(ggcW + (size_t)i*H*H, gBh[i], gBl[i], H, H);

  // ---- x -> split pair (pitch LPH, zero-padded) ----
  cvt_split<<<(int)(((long)NN*LPH + 255)/256), 256, 0, stream>>>(x, xaHi, xaLo, NN, D, LPH);

  // XCD-grouped grids
  const int NPAN = (NN + 127)/128;            // 782
  const int PL8  = (NPAN + 7)/8;              // 98
  const int NJ_G = (H + 127)/128;             // 2
  const int NJ_U = (H + 31)/32;               // 7
  const int GRID_G = 8 * NJ_G * PL8;
  const int GRID_U = 8 * NJ_U * PL8;

  // proj + bn1 + relu : xpair -> hpair
  mgemm<1><<<GRID_G, 256, 0, stream>>>(xaHi, xaLo, pBh, pBl, NN, H, NJ_G, NPAN,
                                       projb, bn1g, bn1b, bn1m, bn1v, hHi, hLo);

  unsigned short *chHi = hHi, *chLo = hLo, *cmHi = mHi, *cmLo = mLo;
  for (int i = 0; i < 3; ++i) {
    mgemm<0><<<GRID_G, 256, 0, stream>>>(chHi, chLo, gBh[i], gBl[i], NN, H, NJ_G, NPAN,
                                         nullptr, nullptr, nullptr, nullptr, nullptr,
                                         cmHi, cmLo);
    gather_k<<<NN, 256, 0, stream>>>(cmHi, cmLo, rowptr, elist, xaHi, xaLo);
    gru6<<<GRID_U, 256, 0, stream>>>(xaHi, xaLo, chHi, chLo,
                                     wihBh, wihBl, whhBh, whhBl,
                                     bih, bhh, NJ_U, NPAN, cmHi, cmLo);
    unsigned short* t;
    t = chHi; chHi = cmHi; cmHi = t;
    t = chLo; chLo = cmLo; cmLo = t;
  }

  pool_g<<<NG, 256, 0, stream>>>(chHi, chLo, batch, bn2g, bn2b, bn2m, bn2v, gmean, gmax);
  fc1_k<<<(NG*H + 255)/256, 256, 0, stream>>>(gmean, gmax, fc1W, fc1b,
                                              bnfg, bnfb, bnfm, bnfv, fc1o);
  fc2_k<<<(NG*2 + 255)/256, 256, 0, stream>>>(fc1o, fc2W, fc2b, (float*)d_out);
}